// Round 10
// baseline (776.413 us; speedup 1.0000x reference)
//
#include <hip/hip_runtime.h>

// RationalQuadratic: 4-layer MLP conditioner (bf16 MFMA GEMMs) + RQ spline.
// R18: (a) launch count 11 -> 5: all prep (3 transposes, W3p, b3p, build_x,
// ld_out zero) merged into one block-range-dispatch kernel. Evidence: every
// round shows ~250-300us residual between dispatch-sum and dur_us (~25us x
// 11 launches). (b) fused GEMM ported to the R17-proven 8-phase schedule at
// 256x192 (M=256 keeps dim-24 alignment; B = 3 x 64-col chunks, each one
// exact 8KB staging pass, 3-bit XOR chunk swizzle -> <=2-way conflicts).
// Same hazard discipline as R17: region restaged only after the phase its
// reads complete in; counted WAITVM(4) only at ph0/ph4; reads consumed
// in-phase (no lgkm asm). gemm_bt kept byte-identical to R17 (verified).

typedef __bf16 bf16_t;
typedef __bf16 bf16x8 __attribute__((ext_vector_type(8)));
typedef float f32x4 __attribute__((ext_vector_type(4)));

#define GLOAD_LDS16(g, l)                                               \
  __builtin_amdgcn_global_load_lds(                                     \
      (const __attribute__((address_space(1))) void*)(g),               \
      (__attribute__((address_space(3))) void*)(l), 16, 0, 0)

#define WAITVM(N) asm volatile("s_waitcnt vmcnt(" #N ")" ::: "memory")
#define SBAR() __builtin_amdgcn_s_barrier()

// Bijective XCD-chunked swizzle (requires nwg % 8 == 0).
__device__ __forceinline__ void xcd_remap(int& bx, int& by) {
  const int gx = gridDim.x;
  const int nwg = gx * gridDim.y;
  const int id = blockIdx.y * gx + blockIdx.x;
  const int nid = (id & 7) * (nwg >> 3) + (id >> 3);
  bx = nid % gx;
  by = nid / gx;
}

// ---------------------------------------------------------------------------
// prep_all: one launch for build_x + ld_out zero + (c==0) all weight prep.
// Block map: [0,Bc) build_x rows; then 64 W0-transpose, 256 W1, 256 W2,
// 384 W3p, 6 b3p = +966.
__global__ __launch_bounds__(256) void prep_all(
    const float* __restrict__ x1, const float* __restrict__ mask1,
    const float* __restrict__ ctx, const float* __restrict__ W0,
    const float* __restrict__ W1, const float* __restrict__ W2,
    const float* __restrict__ W3, const float* __restrict__ b3,
    bf16_t* __restrict__ X, float* __restrict__ ld_out,
    bf16_t* __restrict__ Wt0, bf16_t* __restrict__ Wt1,
    bf16_t* __restrict__ Wt2, bf16_t* __restrict__ Wt3,
    float* __restrict__ b3p, int boff, int Bc) {
  __shared__ float tile[64][65];
  const int tid = threadIdx.x;
  int id = blockIdx.x;
  if (id < Bc) {  // build_x: one row per block
    const int c = tid;
    const size_t b = (size_t)(boff + id);
    float v;
    if (c < 64)       v = x1[b * 64 + c];
    else if (c < 128) v = mask1[b * 64 + (c - 64)];
    else              v = ctx[b * 128 + (c - 128)];
    X[(size_t)id * 256 + c] = (bf16_t)v;
    if (c == 0) ld_out[b] = 0.0f;
    return;
  }
  id -= Bc;
  const int r4 = tid >> 6;
  const int cc = tid & 63;
  const float* W = nullptr;
  bf16_t* Wt = nullptr;
  int K = 0, N = 0, kt = 0, nt = 0;
  bool w3 = false;
  if (id < 64)       { W = W0; Wt = Wt0; K = 256;  N = 1024; kt = (id & 3) * 64;  nt = (id >> 2) * 64; }
  else if (id < 320) { int j = id - 64;  W = W1; Wt = Wt1; K = 1024; N = 1024; kt = (j & 15) * 64; nt = (j >> 4) * 64; }
  else if (id < 576) { int j = id - 320; W = W2; Wt = Wt2; K = 1024; N = 1024; kt = (j & 15) * 64; nt = (j >> 4) * 64; }
  else if (id < 960) { int j = id - 576; K = 1024; kt = (j & 15) * 64; nt = (j >> 4) * 64; w3 = true; }
  else {
    int t = (id - 960) * 256 + tid;
    if (t < 1536) { int d = t / 24, p = t % 24; b3p[t] = (p < 23) ? b3[d * 23 + p] : 0.0f; }
    return;
  }
  if (!w3) {
#pragma unroll
    for (int i = 0; i < 16; i++) {
      int r = i * 4 + r4;
      int gn = nt + cc;
      tile[r][cc] = (gn < N) ? W[(size_t)(kt + r) * N + gn] : 0.0f;
    }
    __syncthreads();
#pragma unroll
    for (int i = 0; i < 16; i++) {
      int r = i * 4 + r4;
      Wt[(size_t)(nt + r) * K + kt + cc] = (bf16_t)tile[cc][r];
    }
  } else {
    const int np = nt + cc, d = np / 24, p = np % 24;
#pragma unroll
    for (int i = 0; i < 16; i++) {
      int r = i * 4 + r4;
      tile[r][cc] = (p < 23) ? W3[(size_t)(kt + r) * 1472 + d * 23 + p] : 0.0f;
    }
    __syncthreads();
#pragma unroll
    for (int i = 0; i < 16; i++) {
      int r = i * 4 + r4;
      Wt3[(size_t)(nt + r) * 1024 + kt + cc] = (bf16_t)tile[cc][r];
    }
  }
}

// ---------------------------------------------------------------------------
// GEMM: 256x256 tile, BK=64, 8 waves 2Mx4N (wave out 128x64, acc[8][4]).
// 8-phase pipelined schedule — byte-identical to R17 (verified, fast).
__global__ __launch_bounds__(512, 2) void gemm_bt(
    const bf16_t* __restrict__ A, const bf16_t* __restrict__ Bt,
    const float* __restrict__ bias, bf16_t* __restrict__ Cout, int N, int K) {
  __shared__ __align__(16) bf16_t sm[65536];  // 128 KB
  const int tid = threadIdx.x;
  const int lane = tid & 63;
  const int w = tid >> 6;
  int bx, by;
  xcd_remap(bx, by);
  const int m0 = by * 256;
  const int n0 = bx * 256;
  const int wmi = w >> 2;
  const int wnj = w & 3;
  const int lrow = lane & 15;
  const int quad = lane >> 4;

  const int byteoff = tid * 16;
  const int srow = byteoff >> 6;
  const int sqs = ((byteoff >> 4) & 3) ^ ((srow >> 1) & 3);
  const bf16_t* gA0 = A + (size_t)(m0 + srow) * K + sqs * 8;
  const bf16_t* gA1 = A + (size_t)(m0 + 128 + srow) * K + sqs * 8;
  const bf16_t* gB0 = Bt + (size_t)(n0 + srow) * K + sqs * 8;
  const bf16_t* gB1 = Bt + (size_t)(n0 + 128 + srow) * K + sqs * 8;
  const int dstT = tid * 8;

#define ST_A(PTR, D, RH)                                                 \
  do {                                                                   \
    GLOAD_LDS16(PTR, sm + (D) * 16384 + (RH) * 8192 + dstT);             \
    GLOAD_LDS16(PTR + 32, sm + (D) * 16384 + (RH) * 8192 + 4096 + dstT); \
    PTR += 64;                                                           \
  } while (0)
#define ST_B(PTR, D, CH)                                                 \
  do {                                                                   \
    GLOAD_LDS16(PTR, sm + 32768 + (D) * 16384 + (CH) * 8192 + dstT);     \
    GLOAD_LDS16(PTR + 32,                                                \
                sm + 32768 + (D) * 16384 + (CH) * 8192 + 4096 + dstT);   \
    PTR += 64;                                                           \
  } while (0)

  int aoff[8];
#pragma unroll
  for (int mi = 0; mi < 8; mi++) {
    const int r = mi * 16 + lrow;
    aoff[mi] = wmi * 8192 + r * 32 + (quad ^ ((r >> 1) & 3)) * 8;
  }
  int boff[4];
#pragma unroll
  for (int nj = 0; nj < 4; nj++) {
    const int c = (wnj & 1) * 64 + nj * 16 + lrow;
    boff[nj] = 32768 + (wnj >> 1) * 8192 + c * 32 + (quad ^ ((c >> 1) & 3)) * 8;
  }

#define RD_AF(DST, D, MIB)                                               \
  _Pragma("unroll") for (int q = 0; q < 4; q++)                          \
    _Pragma("unroll") for (int kk = 0; kk < 2; kk++)                     \
      DST[q][kk] =                                                       \
          *(const bf16x8*)(sm + (D) * 16384 + kk * 4096 + aoff[(MIB) + q]);
#define RD_BF(DST, D, NJB)                                               \
  _Pragma("unroll") for (int q = 0; q < 2; q++)                          \
    _Pragma("unroll") for (int kk = 0; kk < 2; kk++)                     \
      DST[q][kk] =                                                       \
          *(const bf16x8*)(sm + (D) * 16384 + kk * 4096 + boff[(NJB) + q]);
#define MM(AF, BF, MIB, NJB)                                             \
  __builtin_amdgcn_s_setprio(1);                                         \
  _Pragma("unroll") for (int q = 0; q < 4; q++)                          \
    _Pragma("unroll") for (int p = 0; p < 2; p++)                        \
      _Pragma("unroll") for (int kk = 0; kk < 2; kk++)                   \
        acc[(MIB) + q][(NJB) + p] = __builtin_amdgcn_mfma_f32_16x16x32_bf16( \
            AF[q][kk], BF[p][kk], acc[(MIB) + q][(NJB) + p], 0, 0, 0);   \
  __builtin_amdgcn_s_setprio(0);

  f32x4 acc[8][4];
#pragma unroll
  for (int i = 0; i < 8; i++)
#pragma unroll
    for (int j = 0; j < 4; j++) acc[i][j] = (f32x4){0.f, 0.f, 0.f, 0.f};

  ST_A(gA0, 0, 0);
  ST_A(gA1, 0, 1);
  ST_B(gB0, 0, 0);
  ST_B(gB1, 0, 1);
  ST_A(gA0, 1, 0);
  ST_A(gA1, 1, 1);

  const int nI = K >> 7;
  for (int i = 0; i < nI; i++) {
    const bool nl = (i + 1 < nI);
    bf16x8 afA[4][2], afB[4][2], bfrA[2][2], bfrB[2][2];
    WAITVM(4);
    SBAR();
    ST_B(gB0, 1, 0);
    RD_AF(afA, 0, 0);
    RD_BF(bfrA, 0, 0);
    MM(afA, bfrA, 0, 0);
    SBAR();
    ST_B(gB1, 1, 1);
    RD_AF(afB, 0, 4);
    MM(afB, bfrA, 4, 0);
    SBAR();
    if (nl) ST_A(gA0, 0, 0);
    RD_BF(bfrB, 0, 2);
    MM(afA, bfrB, 0, 2);
    SBAR();
    if (nl) ST_A(gA1, 0, 1);
    MM(afB, bfrB, 4, 2);
    if (nl) { WAITVM(4); } else { WAITVM(0); }
    SBAR();
    if (nl) ST_B(gB0, 0, 0);
    RD_AF(afA, 1, 0);
    RD_BF(bfrA, 1, 0);
    MM(afA, bfrA, 0, 0);
    SBAR();
    if (nl) ST_B(gB1, 0, 1);
    RD_AF(afB, 1, 4);
    MM(afB, bfrA, 4, 0);
    SBAR();
    if (nl) ST_A(gA0, 1, 0);
    RD_BF(bfrB, 1, 2);
    MM(afA, bfrB, 0, 2);
    SBAR();
    if (nl) ST_A(gA1, 1, 1);
    MM(afB, bfrB, 4, 2);
  }
#undef ST_A
#undef ST_B
#undef RD_AF
#undef RD_BF
#undef MM

  float bv[4];
#pragma unroll
  for (int j = 0; j < 4; j++) bv[j] = bias[n0 + wnj * 64 + j * 16 + lrow];
#pragma unroll
  for (int i = 0; i < 8; i++) {
    int rbase = m0 + wmi * 128 + i * 16 + quad * 4;
#pragma unroll
    for (int j = 0; j < 4; j++) {
      int col = n0 + wnj * 64 + j * 16 + lrow;
#pragma unroll
      for (int r = 0; r < 4; r++) {
        float v = fmaxf(acc[i][j][r] + bv[j], 0.0f);
        Cout[(size_t)(rbase + r) * N + col] = (bf16_t)v;
      }
    }
  }
}

// ---------------------------------------------------------------------------
// Fused last GEMM + RQ spline, R17-style 8-phase at 256 rows x 192 cols
// (= 8 dims x 24). 8 waves 2Mx4N: wave = 128x48, acc[8][3]. BK=64.
// LDS (elems): A[d][rh][kh] @ d*16384+rh*8192+kh*4096 (quad-XOR swizzle);
// B chunks [64 col][64 k] @ 32768 + d*12288 + ch*4096, 3-bit XOR: position
// p in a col's 8 16B-slots holds data-chunk p^(col&7) (<=2-way reads).
// Staging/tile: A 4 gloads (2 rh x 2 kh), B 3 gloads (1/chunk) = 7; phases
// stage 2,1,2,2,2,1,2,2. vmcnt(4) at ph0/ph4 only. Pt union 256x200 bf16.
__global__ __launch_bounds__(512, 2) void gemm_rq_fused(
    const bf16_t* __restrict__ A, const bf16_t* __restrict__ Bt,
    const float* __restrict__ b3p, const float* __restrict__ x2,
    float* __restrict__ z_out, float* __restrict__ ld_out,
    int boff, int K) {
  __shared__ __align__(16) bf16_t sm[57344];  // 112 KB (>= Pt 51200 elems)
  const int tid = threadIdx.x;
  const int lane = tid & 63;
  const int w = tid >> 6;
  int bx, by;
  xcd_remap(bx, by);
  const int m0 = by * 256;
  const int n0 = bx * 192;
  const int wmi = w >> 2;          // 0..1  M-half (128 rows)
  const int wnj = w & 3;           // 0..3  N-quarter (48 cols)
  const int lrow = lane & 15;
  const int quad = lane >> 4;

  // A staging (identical to gemm_bt).
  const int byteoff = tid * 16;
  const int srow = byteoff >> 6;
  const int sqs = ((byteoff >> 4) & 3) ^ ((srow >> 1) & 3);
  const bf16_t* gA0 = A + (size_t)(m0 + srow) * K + sqs * 8;
  const bf16_t* gA1 = A + (size_t)(m0 + 128 + srow) * K + sqs * 8;
  // B staging: thread t -> chunk elems [t*8,t*8+8): col=t>>3, pos=t&7,
  // data-chunk dc = pos ^ (col&7), source k = dc*8.
  const int scol = tid >> 3;
  const int sdc = (tid & 7) ^ (scol & 7);
  const bf16_t* gB0c = Bt + (size_t)(n0 + scol) * K + sdc * 8;
  const bf16_t* gB1c = Bt + (size_t)(n0 + 64 + scol) * K + sdc * 8;
  const bf16_t* gB2c = Bt + (size_t)(n0 + 128 + scol) * K + sdc * 8;
  const int dstT = tid * 8;

#define FST_A(PTR, D, RH)                                                \
  do {                                                                   \
    GLOAD_LDS16(PTR, sm + (D) * 16384 + (RH) * 8192 + dstT);             \
    GLOAD_LDS16(PTR + 32, sm + (D) * 16384 + (RH) * 8192 + 4096 + dstT); \
    PTR += 64;                                                           \
  } while (0)
#define FST_B(PTR, D, CH)                                                \
  do {                                                                   \
    GLOAD_LDS16(PTR, sm + 32768 + (D) * 12288 + (CH) * 4096 + dstT);     \
    PTR += 64;                                                           \
  } while (0)

  int aoff[8];
#pragma unroll
  for (int mi = 0; mi < 8; mi++) {
    const int r = mi * 16 + lrow;
    aoff[mi] = wmi * 8192 + r * 32 + (quad ^ ((r >> 1) & 3)) * 8;
  }
  int boffs[3][2];
#pragma unroll
  for (int nj = 0; nj < 3; nj++) {
#pragma unroll
    for (int kk = 0; kk < 2; kk++) {
      const int c = wnj * 48 + nj * 16 + lrow;
      const int ch = c >> 6, ccol = c & 63;
      boffs[nj][kk] =
          32768 + ch * 4096 + ccol * 64 + ((((kk << 2) | quad)) ^ (ccol & 7)) * 8;
    }
  }

#define FRD_A(DST, D, MIB)                                               \
  _Pragma("unroll") for (int q = 0; q < 4; q++)                          \
    _Pragma("unroll") for (int kk = 0; kk < 2; kk++)                     \
      DST[q][kk] =                                                       \
          *(const bf16x8*)(sm + (D) * 16384 + kk * 4096 + aoff[(MIB) + q]);
#define FRD_B01(D)                                                       \
  _Pragma("unroll") for (int nj = 0; nj < 2; nj++)                       \
    _Pragma("unroll") for (int kk = 0; kk < 2; kk++)                     \
      bfr[nj][kk] = *(const bf16x8*)(sm + (D) * 12288 + boffs[nj][kk]);
#define FRD_B2(D)                                                        \
  _Pragma("unroll") for (int kk = 0; kk < 2; kk++)                       \
    bfr[2][kk] = *(const bf16x8*)(sm + (D) * 12288 + boffs[2][kk]);
#define FMM16(AF, MIB)                                                   \
  __builtin_amdgcn_s_setprio(1);                                         \
  _Pragma("unroll") for (int q = 0; q < 4; q++)                          \
    _Pragma("unroll") for (int p = 0; p < 2; p++)                        \
      _Pragma("unroll") for (int kk = 0; kk < 2; kk++)                   \
        acc[(MIB) + q][p] = __builtin_amdgcn_mfma_f32_16x16x32_bf16(     \
            AF[q][kk], bfr[p][kk], acc[(MIB) + q][p], 0, 0, 0);          \
  __builtin_amdgcn_s_setprio(0);
#define FMM8(AF, MIB)                                                    \
  __builtin_amdgcn_s_setprio(1);                                         \
  _Pragma("unroll") for (int q = 0; q < 4; q++)                          \
    _Pragma("unroll") for (int kk = 0; kk < 2; kk++)                     \
      acc[(MIB) + q][2] = __builtin_amdgcn_mfma_f32_16x16x32_bf16(       \
          AF[q][kk], bfr[2][kk], acc[(MIB) + q][2], 0, 0, 0);            \
  __builtin_amdgcn_s_setprio(0);

  f32x4 acc[8][3];
#pragma unroll
  for (int i = 0; i < 8; i++)
#pragma unroll
    for (int j = 0; j < 3; j++) acc[i][j] = (f32x4){0.f, 0.f, 0.f, 0.f};

  // Prologue: tile0 (dbuf0) full + tile1 (dbuf1) A. 11 gloads.
  FST_A(gA0, 0, 0);
  FST_A(gA1, 0, 1);
  FST_B(gB0c, 0, 0);
  FST_B(gB1c, 0, 1);
  FST_B(gB2c, 0, 2);
  FST_A(gA0, 1, 0);
  FST_A(gA1, 1, 1);

  const int nI = K >> 7;  // two BK=64 tiles per iteration
  for (int i = 0; i < nI; i++) {
    const bool nl = (i + 1 < nI);
    bf16x8 afA[4][2], afB[4][2], bfr[3][2];
    // ph0: consume dbuf0 (tile 2i): acc[0-3][0-1]
    WAITVM(4);
    SBAR();
    FST_B(gB0c, 1, 0);          // tile 2i+1 B ch0 (dbuf1.B free since prev ph6)
    FST_B(gB1c, 1, 1);          // ch1
    FRD_A(afA, 0, 0);
    FRD_B01(0);
    FMM16(afA, 0);
    // ph1: acc[4-7][0-1]
    SBAR();
    FST_B(gB2c, 1, 2);          // ch2
    FRD_A(afB, 0, 4);
    FMM16(afB, 4);
    // ph2: acc[0-3][2]   [dbuf0.A reads ended ph1 -> restage A]
    SBAR();
    if (nl) FST_A(gA0, 0, 0);   // tile 2i+2 A rh0
    FRD_B2(0);
    FMM8(afA, 0);
    // ph3: acc[4-7][2]
    SBAR();
    if (nl) FST_A(gA1, 0, 1);   // tile 2i+2 A rh1
    FMM8(afB, 4);
    // ph4: consume dbuf1 (tile 2i+1); dbuf0.B reads ended ph2
    if (nl) { WAITVM(4); } else { WAITVM(0); }
    SBAR();
    if (nl) { FST_B(gB0c, 0, 0); FST_B(gB1c, 0, 1); }  // tile 2i+2 B
    FRD_A(afA, 1, 0);
    FRD_B01(1);
    FMM16(afA, 0);
    // ph5
    SBAR();
    if (nl) FST_B(gB2c, 0, 2);
    FRD_A(afB, 1, 4);
    FMM16(afB, 4);
    // ph6: dbuf1.A reads ended ph5
    SBAR();
    if (nl) FST_A(gA0, 1, 0);   // tile 2i+3 A rh0
    FRD_B2(1);
    FMM8(afA, 0);
    // ph7
    SBAR();
    if (nl) FST_A(gA1, 1, 1);   // tile 2i+3 A rh1
    FMM8(afB, 4);
  }
#undef FST_A
#undef FST_B
#undef FRD_A
#undef FRD_B01
#undef FRD_B2
#undef FMM16
#undef FMM8
  __syncthreads();  // all LDS reads done before Pt overwrites the union

  // --- P-tile (bf16, +bias) into LDS. C/D layout: col=lane&15, row=quad*4+r.
  float bv[3];
#pragma unroll
  for (int j = 0; j < 3; j++) bv[j] = b3p[n0 + wnj * 48 + j * 16 + lrow];
#pragma unroll
  for (int i = 0; i < 8; i++) {
    const int rbase = wmi * 128 + i * 16 + quad * 4;
#pragma unroll
    for (int j = 0; j < 3; j++) {
      const int col = wnj * 48 + j * 16 + lrow;
#pragma unroll
      for (int r = 0; r < 4; r++)
        sm[(rbase + r) * 200 + col] = (bf16_t)(acc[i][j][r] + bv[j]);
    }
  }
  __syncthreads();

  // --- spline: thread t -> dim t&7, rows (t>>3)+rr*64, rr=0..3.
  const float SHIFT = 0.54132485f;     // log(e-1)
  const float SHIFT_DX = 5.1944682f;   // log(exp(6.0-0.8)-1)
  const float left = -3.0f;
  const float delta_x = 0.8f + log1pf(expf(SHIFT_DX));
  const float right = left + delta_x;
  const float scale = delta_x;
  const int dloc = tid & 7;
  const int dg = bx * 8 + dloc;

#pragma unroll
  for (int rr = 0; rr < 4; rr++) {
    const int row = (tid >> 3) + rr * 64;
    const bf16_t* pr = sm + row * 200 + dloc * 24;
    const size_t bg = (size_t)(boff + m0 + row);
    const float x = x2[bg * 64 + dg];

    bf16x8 v0 = *(const bf16x8*)(pr);
    bf16x8 v1 = *(const bf16x8*)(pr + 8);
    bf16x8 v2 = *(const bf16x8*)(pr + 16);
    float pv[24];
#pragma unroll
    for (int j = 0; j < 8; j++) pv[j] = (float)v0[j];
#pragma unroll
    for (int j = 0; j < 8; j++) pv[8 + j] = (float)v1[j];
#pragma unroll
    for (int j = 0; j < 8; j++) pv[16 + j] = (float)v2[j];

    float mw = pv[0];
#pragma unroll
    for (int j = 1; j < 8; j++) mw = fmaxf(mw, pv[j]);
    float ew[8], swv = 0.f;
#pragma unroll
    for (int j = 0; j < 8; j++) { ew[j] = expf(pv[j] - mw); swv += ew[j]; }
    float invw = 1.0f / swv;
    float cw[9];
    cw[0] = left;
    float cum = 0.f;
#pragma unroll
    for (int j = 0; j < 8; j++) {
      cum += 0.1f + 0.2f * ew[j] * invw;
      cw[j + 1] = left + scale * cum;
    }
    float mh = pv[8];
#pragma unroll
    for (int j = 9; j < 16; j++) mh = fmaxf(mh, pv[j]);
    float eh[8], shv = 0.f;
#pragma unroll
    for (int j = 0; j < 8; j++) { eh[j] = expf(pv[8 + j] - mh); shv += eh[j]; }
    float invh = 1.0f / shv;
    float chh[9];
    chh[0] = left;
    float cumh = 0.f;
#pragma unroll
    for (int j = 0; j < 8; j++) {
      cumh += 0.1f + 0.2f * eh[j] * invh;
      chh[j + 1] = left + scale * cumh;
    }
    float dv[9];
    dv[0] = 1.0f;
    dv[8] = 1.0f;
#pragma unroll
    for (int j = 0; j < 7; j++) {
      float v = pv[16 + j] + SHIFT;
      dv[j + 1] = 0.001f + ((v > 20.f) ? v : log1pf(expf(v)));
    }
    int cnt = 0;
#pragma unroll
    for (int j = 0; j < 8; j++) cnt += (cw[j] <= x) ? 1 : 0;
    cnt += ((cw[8] + 1e-6f) <= x) ? 1 : 0;
    int idx = cnt - 1;
    idx = idx < 0 ? 0 : (idx > 7 ? 7 : idx);
    float x_k = cw[0], x_k1 = cw[1], y_k = chh[0], y_k1 = chh[1];
    float d0v = dv[0], d1v = dv[1];
#pragma unroll
    for (int j = 1; j < 8; j++) {
      bool s = (idx == j);
      x_k = s ? cw[j] : x_k;
      x_k1 = s ? cw[j + 1] : x_k1;
      y_k = s ? chh[j] : y_k;
      y_k1 = s ? chh[j + 1] : y_k1;
      d0v = s ? dv[j] : d0v;
      d1v = s ? dv[j + 1] : d1v;
    }
    float x_kd = x_k1 - x_k;
    float y_kd = y_k1 - y_k;
    float s_k = y_kd / x_kd;
    float xi = (x - x_k) / x_kd;
    float xi1m = xi * (1.f - xi);
    float alpha_k = y_kd * (s_k * xi * xi + d0v * xi1m);
    float beta_k = s_k + (d1v + d0v - 2.f * s_k) * xi1m;
    float z_sp = y_k + alpha_k / fmaxf(beta_k, 1e-8f);
    float oxi = 1.f - xi;
    float num = s_k * s_k * (d1v * xi * xi + 2.f * s_k * xi1m + d0v * oxi * oxi);
    float ld_sp = logf(fmaxf(num, 1e-8f)) - 2.f * logf(fmaxf(beta_k, 1e-8f));

    bool inside = (left <= x) && (x < right);
    z_out[bg * 64 + dg] = inside ? z_sp : x;
    float ldv = inside ? ld_sp : 0.f;
    ldv += __shfl_xor(ldv, 1);
    ldv += __shfl_xor(ldv, 2);
    ldv += __shfl_xor(ldv, 4);
    if (dloc == 0) atomicAdd(&ld_out[bg], ldv);
  }
}

// ---------------------------------------------------------------------------
extern "C" void kernel_launch(void* const* d_in, const int* in_sizes, int n_in,
                              void* d_out, int out_size, void* d_ws,
                              size_t ws_size, hipStream_t stream) {
  const float* x1 = (const float*)d_in[0];
  const float* x2 = (const float*)d_in[1];
  const float* ctx = (const float*)d_in[2];
  const float* mask1 = (const float*)d_in[3];
  const float* W0 = (const float*)d_in[4];
  const float* b0 = (const float*)d_in[5];
  const float* W1 = (const float*)d_in[6];
  const float* b1 = (const float*)d_in[7];
  const float* W2 = (const float*)d_in[8];
  const float* b2 = (const float*)d_in[9];
  const float* W3 = (const float*)d_in[10];
  const float* b3 = (const float*)d_in[11];
  float* out = (float*)d_out;

  const int B = 65536;
  char* ws = (char*)d_ws;

  bf16_t* Wt0 = (bf16_t*)ws;                           // 1024x256  (512 KB)
  bf16_t* Wt1 = (bf16_t*)(ws + 524288);                // 1024x1024 (2 MB)
  bf16_t* Wt2 = (bf16_t*)(ws + 524288 + 2097152);      // 1024x1024 (2 MB)
  bf16_t* Wt3 = (bf16_t*)(ws + 524288 + 2 * 2097152);  // 1536x1024 (3 MB)
  float* b3p = (float*)(ws + 524288 + 2 * 2097152 + 3145728);  // 6 KB
  const size_t wend = 524288 + 2 * 2097152 + 3145728 + 8192;

  int C = 4;
  if (wend + (size_t)B * 4096 <= ws_size) C = 1;
  else if (wend + (size_t)(B / 2) * 4096 <= ws_size) C = 2;
  const int Bc = B / C;
  bf16_t* HA = (bf16_t*)(ws + wend);
  char* R = ws + wend + (size_t)Bc * 2048;
  bf16_t* X = (bf16_t*)R;
  bf16_t* HB = (bf16_t*)R;
  float* ld_out = out + (size_t)B * 64;

  for (int c = 0; c < C; c++) {
    const int boff = c * Bc;
    prep_all<<<Bc + (c == 0 ? 966 : 0), 256, 0, stream>>>(
        x1, mask1, ctx, W0, W1, W2, W3, b3, X, ld_out,
        Wt0, Wt1, Wt2, Wt3, b3p, boff, Bc);
    gemm_bt<<<dim3(4, Bc / 256), 512, 0, stream>>>(X, Wt0, b0, HA, 1024, 256);
    gemm_bt<<<dim3(4, Bc / 256), 512, 0, stream>>>(HA, Wt1, b1, HB, 1024, 1024);
    gemm_bt<<<dim3(4, Bc / 256), 512, 0, stream>>>(HB, Wt2, b2, HA, 1024, 1024);
    gemm_rq_fused<<<dim3(8, Bc / 256), 512, 0, stream>>>(
        HA, Wt3, b3p, x2, out, ld_out, boff, 1024);
  }
}

// Round 11
// 740.901 us; speedup vs baseline: 1.0479x; 1.0479x over previous
//
#include <hip/hip_runtime.h>

// RationalQuadratic: 4-layer MLP conditioner (bf16 MFMA GEMMs) + RQ spline.
// R19: recombination of proven parts. R18 split: prep_all merge = -65us
// (launch overhead ~11us/launch, confirmed); fused 8-phase port = +85us
// LOSS (LDS 112KB -> 1 block/CU, FMM8 phases only 8 MFMA vs barrier cost,
// no cross-block cover). So: prep_all (R18) + 8-phase 256^2 gemm_bt (R17,
// the +55us win over the 2-barrier ceiling) + fused kernel reverted to the
// R15 form (163us proven: 128x192 2-barrier, bf16 Pt union, 3 blocks/CU).

typedef __bf16 bf16_t;
typedef __bf16 bf16x8 __attribute__((ext_vector_type(8)));
typedef float f32x4 __attribute__((ext_vector_type(4)));

#define GLOAD_LDS16(g, l)                                               \
  __builtin_amdgcn_global_load_lds(                                     \
      (const __attribute__((address_space(1))) void*)(g),               \
      (__attribute__((address_space(3))) void*)(l), 16, 0, 0)

#define WAITVM(N) asm volatile("s_waitcnt vmcnt(" #N ")" ::: "memory")
#define SBAR() __builtin_amdgcn_s_barrier()

// Bijective XCD-chunked swizzle (requires nwg % 8 == 0).
__device__ __forceinline__ void xcd_remap(int& bx, int& by) {
  const int gx = gridDim.x;
  const int nwg = gx * gridDim.y;
  const int id = blockIdx.y * gx + blockIdx.x;
  const int nid = (id & 7) * (nwg >> 3) + (id >> 3);
  bx = nid % gx;
  by = nid / gx;
}

// ---------------------------------------------------------------------------
// prep_all: one launch for build_x + ld_out zero + (c==0) all weight prep.
// Block map: [0,Bc) build_x rows; then 64 W0-transpose, 256 W1, 256 W2,
// 384 W3p, 6 b3p = +966.
__global__ __launch_bounds__(256) void prep_all(
    const float* __restrict__ x1, const float* __restrict__ mask1,
    const float* __restrict__ ctx, const float* __restrict__ W0,
    const float* __restrict__ W1, const float* __restrict__ W2,
    const float* __restrict__ W3, const float* __restrict__ b3,
    bf16_t* __restrict__ X, float* __restrict__ ld_out,
    bf16_t* __restrict__ Wt0, bf16_t* __restrict__ Wt1,
    bf16_t* __restrict__ Wt2, bf16_t* __restrict__ Wt3,
    float* __restrict__ b3p, int boff, int Bc) {
  __shared__ float tile[64][65];
  const int tid = threadIdx.x;
  int id = blockIdx.x;
  if (id < Bc) {  // build_x: one row per block
    const int c = tid;
    const size_t b = (size_t)(boff + id);
    float v;
    if (c < 64)       v = x1[b * 64 + c];
    else if (c < 128) v = mask1[b * 64 + (c - 64)];
    else              v = ctx[b * 128 + (c - 128)];
    X[(size_t)id * 256 + c] = (bf16_t)v;
    if (c == 0) ld_out[b] = 0.0f;
    return;
  }
  id -= Bc;
  const int r4 = tid >> 6;
  const int cc = tid & 63;
  const float* W = nullptr;
  bf16_t* Wt = nullptr;
  int K = 0, N = 0, kt = 0, nt = 0;
  bool w3 = false;
  if (id < 64)       { W = W0; Wt = Wt0; K = 256;  N = 1024; kt = (id & 3) * 64;  nt = (id >> 2) * 64; }
  else if (id < 320) { int j = id - 64;  W = W1; Wt = Wt1; K = 1024; N = 1024; kt = (j & 15) * 64; nt = (j >> 4) * 64; }
  else if (id < 576) { int j = id - 320; W = W2; Wt = Wt2; K = 1024; N = 1024; kt = (j & 15) * 64; nt = (j >> 4) * 64; }
  else if (id < 960) { int j = id - 576; K = 1024; kt = (j & 15) * 64; nt = (j >> 4) * 64; w3 = true; }
  else {
    int t = (id - 960) * 256 + tid;
    if (t < 1536) { int d = t / 24, p = t % 24; b3p[t] = (p < 23) ? b3[d * 23 + p] : 0.0f; }
    return;
  }
  if (!w3) {
#pragma unroll
    for (int i = 0; i < 16; i++) {
      int r = i * 4 + r4;
      int gn = nt + cc;
      tile[r][cc] = (gn < N) ? W[(size_t)(kt + r) * N + gn] : 0.0f;
    }
    __syncthreads();
#pragma unroll
    for (int i = 0; i < 16; i++) {
      int r = i * 4 + r4;
      Wt[(size_t)(nt + r) * K + kt + cc] = (bf16_t)tile[cc][r];
    }
  } else {
    const int np = nt + cc, d = np / 24, p = np % 24;
#pragma unroll
    for (int i = 0; i < 16; i++) {
      int r = i * 4 + r4;
      tile[r][cc] = (p < 23) ? W3[(size_t)(kt + r) * 1472 + d * 23 + p] : 0.0f;
    }
    __syncthreads();
#pragma unroll
    for (int i = 0; i < 16; i++) {
      int r = i * 4 + r4;
      Wt3[(size_t)(nt + r) * 1024 + kt + cc] = (bf16_t)tile[cc][r];
    }
  }
}

// ---------------------------------------------------------------------------
// GEMM: 256x256 tile, BK=64, 8 waves 2Mx4N (wave out 128x64, acc[8][4]).
// 8-phase pipelined schedule — byte-identical to R17 (verified, fast).
__global__ __launch_bounds__(512, 2) void gemm_bt(
    const bf16_t* __restrict__ A, const bf16_t* __restrict__ Bt,
    const float* __restrict__ bias, bf16_t* __restrict__ Cout, int N, int K) {
  __shared__ __align__(16) bf16_t sm[65536];  // 128 KB
  const int tid = threadIdx.x;
  const int lane = tid & 63;
  const int w = tid >> 6;
  int bx, by;
  xcd_remap(bx, by);
  const int m0 = by * 256;
  const int n0 = bx * 256;
  const int wmi = w >> 2;
  const int wnj = w & 3;
  const int lrow = lane & 15;
  const int quad = lane >> 4;

  const int byteoff = tid * 16;
  const int srow = byteoff >> 6;
  const int sqs = ((byteoff >> 4) & 3) ^ ((srow >> 1) & 3);
  const bf16_t* gA0 = A + (size_t)(m0 + srow) * K + sqs * 8;
  const bf16_t* gA1 = A + (size_t)(m0 + 128 + srow) * K + sqs * 8;
  const bf16_t* gB0 = Bt + (size_t)(n0 + srow) * K + sqs * 8;
  const bf16_t* gB1 = Bt + (size_t)(n0 + 128 + srow) * K + sqs * 8;
  const int dstT = tid * 8;

#define ST_A(PTR, D, RH)                                                 \
  do {                                                                   \
    GLOAD_LDS16(PTR, sm + (D) * 16384 + (RH) * 8192 + dstT);             \
    GLOAD_LDS16(PTR + 32, sm + (D) * 16384 + (RH) * 8192 + 4096 + dstT); \
    PTR += 64;                                                           \
  } while (0)
#define ST_B(PTR, D, CH)                                                 \
  do {                                                                   \
    GLOAD_LDS16(PTR, sm + 32768 + (D) * 16384 + (CH) * 8192 + dstT);     \
    GLOAD_LDS16(PTR + 32,                                                \
                sm + 32768 + (D) * 16384 + (CH) * 8192 + 4096 + dstT);   \
    PTR += 64;                                                           \
  } while (0)

  int aoff[8];
#pragma unroll
  for (int mi = 0; mi < 8; mi++) {
    const int r = mi * 16 + lrow;
    aoff[mi] = wmi * 8192 + r * 32 + (quad ^ ((r >> 1) & 3)) * 8;
  }
  int boff[4];
#pragma unroll
  for (int nj = 0; nj < 4; nj++) {
    const int c = (wnj & 1) * 64 + nj * 16 + lrow;
    boff[nj] = 32768 + (wnj >> 1) * 8192 + c * 32 + (quad ^ ((c >> 1) & 3)) * 8;
  }

#define RD_AF(DST, D, MIB)                                               \
  _Pragma("unroll") for (int q = 0; q < 4; q++)                          \
    _Pragma("unroll") for (int kk = 0; kk < 2; kk++)                     \
      DST[q][kk] =                                                       \
          *(const bf16x8*)(sm + (D) * 16384 + kk * 4096 + aoff[(MIB) + q]);
#define RD_BF(DST, D, NJB)                                               \
  _Pragma("unroll") for (int q = 0; q < 2; q++)                          \
    _Pragma("unroll") for (int kk = 0; kk < 2; kk++)                     \
      DST[q][kk] =                                                       \
          *(const bf16x8*)(sm + (D) * 16384 + kk * 4096 + boff[(NJB) + q]);
#define MM(AF, BF, MIB, NJB)                                             \
  __builtin_amdgcn_s_setprio(1);                                         \
  _Pragma("unroll") for (int q = 0; q < 4; q++)                          \
    _Pragma("unroll") for (int p = 0; p < 2; p++)                        \
      _Pragma("unroll") for (int kk = 0; kk < 2; kk++)                   \
        acc[(MIB) + q][(NJB) + p] = __builtin_amdgcn_mfma_f32_16x16x32_bf16( \
            AF[q][kk], BF[p][kk], acc[(MIB) + q][(NJB) + p], 0, 0, 0);   \
  __builtin_amdgcn_s_setprio(0);

  f32x4 acc[8][4];
#pragma unroll
  for (int i = 0; i < 8; i++)
#pragma unroll
    for (int j = 0; j < 4; j++) acc[i][j] = (f32x4){0.f, 0.f, 0.f, 0.f};

  ST_A(gA0, 0, 0);
  ST_A(gA1, 0, 1);
  ST_B(gB0, 0, 0);
  ST_B(gB1, 0, 1);
  ST_A(gA0, 1, 0);
  ST_A(gA1, 1, 1);

  const int nI = K >> 7;
  for (int i = 0; i < nI; i++) {
    const bool nl = (i + 1 < nI);
    bf16x8 afA[4][2], afB[4][2], bfrA[2][2], bfrB[2][2];
    WAITVM(4);
    SBAR();
    ST_B(gB0, 1, 0);
    RD_AF(afA, 0, 0);
    RD_BF(bfrA, 0, 0);
    MM(afA, bfrA, 0, 0);
    SBAR();
    ST_B(gB1, 1, 1);
    RD_AF(afB, 0, 4);
    MM(afB, bfrA, 4, 0);
    SBAR();
    if (nl) ST_A(gA0, 0, 0);
    RD_BF(bfrB, 0, 2);
    MM(afA, bfrB, 0, 2);
    SBAR();
    if (nl) ST_A(gA1, 0, 1);
    MM(afB, bfrB, 4, 2);
    if (nl) { WAITVM(4); } else { WAITVM(0); }
    SBAR();
    if (nl) ST_B(gB0, 0, 0);
    RD_AF(afA, 1, 0);
    RD_BF(bfrA, 1, 0);
    MM(afA, bfrA, 0, 0);
    SBAR();
    if (nl) ST_B(gB1, 0, 1);
    RD_AF(afB, 1, 4);
    MM(afB, bfrA, 4, 0);
    SBAR();
    if (nl) ST_A(gA0, 1, 0);
    RD_BF(bfrB, 1, 2);
    MM(afA, bfrB, 0, 2);
    SBAR();
    if (nl) ST_A(gA1, 1, 1);
    MM(afB, bfrB, 4, 2);
  }
#undef ST_A
#undef ST_B
#undef RD_AF
#undef RD_BF
#undef MM

  float bv[4];
#pragma unroll
  for (int j = 0; j < 4; j++) bv[j] = bias[n0 + wnj * 64 + j * 16 + lrow];
#pragma unroll
  for (int i = 0; i < 8; i++) {
    int rbase = m0 + wmi * 128 + i * 16 + quad * 4;
#pragma unroll
    for (int j = 0; j < 4; j++) {
      int col = n0 + wnj * 64 + j * 16 + lrow;
#pragma unroll
      for (int r = 0; r < 4; r++) {
        float v = fmaxf(acc[i][j][r] + bv[j], 0.0f);
        Cout[(size_t)(rbase + r) * N + col] = (bf16_t)v;
      }
    }
  }
}

// ---------------------------------------------------------------------------
// Fused last GEMM + RQ spline (R15 form, proven 163us). Tile 128x192
// (= 8 dims x 24 padded params), 8 waves 2x4, wave 64x48. bf16 Pt union
// (stride 200, 51200B -> 3 blocks/CU). XCD-chunked remap.
__global__ __launch_bounds__(512, 4) void gemm_rq_fused(
    const bf16_t* __restrict__ A, const bf16_t* __restrict__ Bt,
    const float* __restrict__ b3p, const float* __restrict__ x2,
    float* __restrict__ z_out, float* __restrict__ ld_out,
    int boff, int K) {
  union alignas(16) SM {
    struct { bf16_t As[2][128 * 32]; bf16_t Bs[2][192 * 32]; } s;  // 40960 B
    bf16_t Pt[128 * 200];                                          // 51200 B
  };
  __shared__ SM sm;
  const int tid = threadIdx.x;
  const int w = tid >> 6;          // 0..7
  const int lane = tid & 63;
  int bx, by;
  xcd_remap(bx, by);
  const int m0 = by * 128;
  const int n0 = bx * 192;
  const int wm = (w & 1) * 64;
  const int wn = (w >> 1) * 48;    // 0..144
  const int lrow = lane & 15;
  const int quad = lane >> 4;

  bf16_t* const smB = &sm.s.As[0][0];
  // Layout (elems): As[0]@0, As[1]@4096, Bs[0]@8192, Bs[1]@14336.

  const bf16_t* gA;
  {
    const int byteoff = (w << 10) + lane * 16;
    const int row = byteoff >> 6;
    const int qs = ((byteoff >> 4) & 3) ^ ((row >> 1) & 3);
    gA = A + (size_t)(m0 + row) * K + qs * 8;
  }
  const bf16_t* gB0;
  const bf16_t* gB1;
  {
    int byteoff = (w << 10) + lane * 16;
    int row = byteoff >> 6;
    int qs = ((byteoff >> 4) & 3) ^ ((row >> 1) & 3);
    gB0 = Bt + (size_t)(n0 + row) * K + qs * 8;
    const int c1 = (w & 3) + 8;              // only used when w < 4
    byteoff = (c1 << 10) + lane * 16;
    row = byteoff >> 6;
    qs = ((byteoff >> 4) & 3) ^ ((row >> 1) & 3);
    gB1 = Bt + (size_t)(n0 + row) * K + qs * 8;
  }
  bf16_t* const dA0 = smB + w * 512;                    // h=1 at +4096
  bf16_t* const dB0 = smB + 8192 + w * 512;             // h=1 at +6144
  bf16_t* const dB1 = smB + 8192 + ((w & 3) + 8) * 512;

  int offA[4], offB3[3];
#pragma unroll
  for (int i = 0; i < 4; i++) {
    const int rowA = wm + i * 16 + lrow;
    offA[i] = rowA * 32 + (quad ^ ((rowA >> 1) & 3)) * 8;
  }
#pragma unroll
  for (int j = 0; j < 3; j++) {
    const int rowB = wn + j * 16 + lrow;
    offB3[j] = rowB * 32 + (quad ^ ((rowB >> 1) & 3)) * 8;
  }

  f32x4 acc[4][3];
#pragma unroll
  for (int i = 0; i < 4; i++)
#pragma unroll
    for (int j = 0; j < 3; j++) acc[i][j] = (f32x4){0.f, 0.f, 0.f, 0.f};

  const int nPair = K >> 6;
  for (int kp = 0; kp < nPair; kp++) {
    GLOAD_LDS16(gA, dA0);
    GLOAD_LDS16(gA + 32, dA0 + 4096);
    GLOAD_LDS16(gB0, dB0);
    GLOAD_LDS16(gB0 + 32, dB0 + 6144);
    if (w < 4) {  // wave-uniform
      GLOAD_LDS16(gB1, dB1);
      GLOAD_LDS16(gB1 + 32, dB1 + 6144);
      gB1 += 64;
    }
    gA += 64;
    gB0 += 64;
    __syncthreads();
#pragma unroll
    for (int h = 0; h < 2; h++) {
      bf16x8 af[4], bfr[3];
#pragma unroll
      for (int i = 0; i < 4; i++)
        af[i] = *(const bf16x8*)(smB + h * 4096 + offA[i]);
#pragma unroll
      for (int j = 0; j < 3; j++)
        bfr[j] = *(const bf16x8*)(smB + 8192 + h * 6144 + offB3[j]);
#pragma unroll
      for (int i = 0; i < 4; i++)
#pragma unroll
        for (int j = 0; j < 3; j++)
          acc[i][j] = __builtin_amdgcn_mfma_f32_16x16x32_bf16(
              af[i], bfr[j], acc[i][j], 0, 0, 0);
    }
    __syncthreads();
  }

  // --- P-tile (bf16, +bias) into LDS. C/D layout: col=lane&15, row=quad*4+r.
  float bv[3];
#pragma unroll
  for (int j = 0; j < 3; j++) bv[j] = b3p[n0 + wn + j * 16 + lrow];
#pragma unroll
  for (int i = 0; i < 4; i++) {
    const int rbase = wm + i * 16 + quad * 4;
#pragma unroll
    for (int j = 0; j < 3; j++) {
      const int col = wn + j * 16 + lrow;
#pragma unroll
      for (int r = 0; r < 4; r++)
        sm.Pt[(rbase + r) * 200 + col] = (bf16_t)(acc[i][j][r] + bv[j]);
    }
  }
  __syncthreads();

  // --- spline: thread t handles rows (t>>3) and (t>>3)+64, dim t&7.
  const float SHIFT = 0.54132485f;     // log(e-1)
  const float SHIFT_DX = 5.1944682f;   // log(exp(6.0-0.8)-1)
  const float left = -3.0f;
  const float delta_x = 0.8f + log1pf(expf(SHIFT_DX));
  const float right = left + delta_x;
  const float scale = delta_x;
  const int dloc = tid & 7;
  const int dg = bx * 8 + dloc;

#pragma unroll
  for (int rr = 0; rr < 2; rr++) {
    const int row = (tid >> 3) + rr * 64;
    const bf16_t* pr = sm.Pt + row * 200 + dloc * 24;
    const size_t bg = (size_t)(boff + m0 + row);
    const float x = x2[bg * 64 + dg];

    bf16x8 v0 = *(const bf16x8*)(pr);
    bf16x8 v1 = *(const bf16x8*)(pr + 8);
    bf16x8 v2 = *(const bf16x8*)(pr + 16);
    float pv[24];
#pragma unroll
    for (int j = 0; j < 8; j++) pv[j] = (float)v0[j];
#pragma unroll
    for (int j = 0; j < 8; j++) pv[8 + j] = (float)v1[j];
#pragma unroll
    for (int j = 0; j < 8; j++) pv[16 + j] = (float)v2[j];

    float mw = pv[0];
#pragma unroll
    for (int j = 1; j < 8; j++) mw = fmaxf(mw, pv[j]);
    float ew[8], swv = 0.f;
#pragma unroll
    for (int j = 0; j < 8; j++) { ew[j] = expf(pv[j] - mw); swv += ew[j]; }
    float invw = 1.0f / swv;
    float cw[9];
    cw[0] = left;
    float cum = 0.f;
#pragma unroll
    for (int j = 0; j < 8; j++) {
      cum += 0.1f + 0.2f * ew[j] * invw;
      cw[j + 1] = left + scale * cum;
    }
    float mh = pv[8];
#pragma unroll
    for (int j = 9; j < 16; j++) mh = fmaxf(mh, pv[j]);
    float eh[8], shv = 0.f;
#pragma unroll
    for (int j = 0; j < 8; j++) { eh[j] = expf(pv[8 + j] - mh); shv += eh[j]; }
    float invh = 1.0f / shv;
    float chh[9];
    chh[0] = left;
    float cumh = 0.f;
#pragma unroll
    for (int j = 0; j < 8; j++) {
      cumh += 0.1f + 0.2f * eh[j] * invh;
      chh[j + 1] = left + scale * cumh;
    }
    float dv[9];
    dv[0] = 1.0f;
    dv[8] = 1.0f;
#pragma unroll
    for (int j = 0; j < 7; j++) {
      float v = pv[16 + j] + SHIFT;
      dv[j + 1] = 0.001f + ((v > 20.f) ? v : log1pf(expf(v)));
    }
    int cnt = 0;
#pragma unroll
    for (int j = 0; j < 8; j++) cnt += (cw[j] <= x) ? 1 : 0;
    cnt += ((cw[8] + 1e-6f) <= x) ? 1 : 0;
    int idx = cnt - 1;
    idx = idx < 0 ? 0 : (idx > 7 ? 7 : idx);
    float x_k = cw[0], x_k1 = cw[1], y_k = chh[0], y_k1 = chh[1];
    float d0v = dv[0], d1v = dv[1];
#pragma unroll
    for (int j = 1; j < 8; j++) {
      bool s = (idx == j);
      x_k = s ? cw[j] : x_k;
      x_k1 = s ? cw[j + 1] : x_k1;
      y_k = s ? chh[j] : y_k;
      y_k1 = s ? chh[j + 1] : y_k1;
      d0v = s ? dv[j] : d0v;
      d1v = s ? dv[j + 1] : d1v;
    }
    float x_kd = x_k1 - x_k;
    float y_kd = y_k1 - y_k;
    float s_k = y_kd / x_kd;
    float xi = (x - x_k) / x_kd;
    float xi1m = xi * (1.f - xi);
    float alpha_k = y_kd * (s_k * xi * xi + d0v * xi1m);
    float beta_k = s_k + (d1v + d0v - 2.f * s_k) * xi1m;
    float z_sp = y_k + alpha_k / fmaxf(beta_k, 1e-8f);
    float oxi = 1.f - xi;
    float num = s_k * s_k * (d1v * xi * xi + 2.f * s_k * xi1m + d0v * oxi * oxi);
    float ld_sp = logf(fmaxf(num, 1e-8f)) - 2.f * logf(fmaxf(beta_k, 1e-8f));

    bool inside = (left <= x) && (x < right);
    z_out[bg * 64 + dg] = inside ? z_sp : x;
    float ldv = inside ? ld_sp : 0.f;
    ldv += __shfl_xor(ldv, 1);
    ldv += __shfl_xor(ldv, 2);
    ldv += __shfl_xor(ldv, 4);
    if (dloc == 0) atomicAdd(&ld_out[bg], ldv);
  }
}

// ---------------------------------------------------------------------------
extern "C" void kernel_launch(void* const* d_in, const int* in_sizes, int n_in,
                              void* d_out, int out_size, void* d_ws,
                              size_t ws_size, hipStream_t stream) {
  const float* x1 = (const float*)d_in[0];
  const float* x2 = (const float*)d_in[1];
  const float* ctx = (const float*)d_in[2];
  const float* mask1 = (const float*)d_in[3];
  const float* W0 = (const float*)d_in[4];
  const float* b0 = (const float*)d_in[5];
  const float* W1 = (const float*)d_in[6];
  const float* b1 = (const float*)d_in[7];
  const float* W2 = (const float*)d_in[8];
  const float* b2 = (const float*)d_in[9];
  const float* W3 = (const float*)d_in[10];
  const float* b3 = (const float*)d_in[11];
  float* out = (float*)d_out;

  const int B = 65536;
  char* ws = (char*)d_ws;

  bf16_t* Wt0 = (bf16_t*)ws;                           // 1024x256  (512 KB)
  bf16_t* Wt1 = (bf16_t*)(ws + 524288);                // 1024x1024 (2 MB)
  bf16_t* Wt2 = (bf16_t*)(ws + 524288 + 2097152);      // 1024x1024 (2 MB)
  bf16_t* Wt3 = (bf16_t*)(ws + 524288 + 2 * 2097152);  // 1536x1024 (3 MB)
  float* b3p = (float*)(ws + 524288 + 2 * 2097152 + 3145728);  // 6 KB
  const size_t wend = 524288 + 2 * 2097152 + 3145728 + 8192;

  int C = 4;
  if (wend + (size_t)B * 4096 <= ws_size) C = 1;
  else if (wend + (size_t)(B / 2) * 4096 <= ws_size) C = 2;
  const int Bc = B / C;
  bf16_t* HA = (bf16_t*)(ws + wend);
  char* R = ws + wend + (size_t)Bc * 2048;
  bf16_t* X = (bf16_t*)R;
  bf16_t* HB = (bf16_t*)R;
  float* ld_out = out + (size_t)B * 64;

  for (int c = 0; c < C; c++) {
    const int boff = c * Bc;
    prep_all<<<Bc + (c == 0 ? 966 : 0), 256, 0, stream>>>(
        x1, mask1, ctx, W0, W1, W2, W3, b3, X, ld_out,
        Wt0, Wt1, Wt2, Wt3, b3p, boff, Bc);
    gemm_bt<<<dim3(4, Bc / 256), 512, 0, stream>>>(X, Wt0, b0, HA, 1024, 256);
    gemm_bt<<<dim3(4, Bc / 256), 512, 0, stream>>>(HA, Wt1, b1, HB, 1024, 1024);
    gemm_bt<<<dim3(4, Bc / 256), 512, 0, stream>>>(HB, Wt2, b2, HA, 1024, 1024);
    gemm_rq_fused<<<dim3(8, Bc / 128), 512, 0, stream>>>(
        HA, Wt3, b3p, x2, out, ld_out, boff, 1024);
  }
}

// Round 12
// 736.776 us; speedup vs baseline: 1.0538x; 1.0056x over previous
//
#include <hip/hip_runtime.h>

// RationalQuadratic: 4-layer MLP conditioner (bf16 MFMA GEMMs) + RQ spline.
// R20: R19 (best, 741us) + two mechanism-backed micro-changes:
// (1) prep_all's build_x: 65536 one-row blocks -> 2048 grid-strided blocks
//     (G11: tiny-block dispatch machinery dominated a 100MB copy).
// (2) spline epilogue: expf/logf -> __expf/__logf (~20us device-wide VALU
//     tail; __expf ~1ulp vs absmax 0.03125 bf16-dominated -> safe).
// NOTE (rule #19 recalibration): identical fused source measured 163/193/
// 161/194 across R15-R19 -> +-30us co-compile variance on that dispatch;
// sub-30us single-round fused deltas are noise. Schedule edits frozen:
// gemm_bt = R17 8-phase (verified win), fused = R15 2-barrier form.

typedef __bf16 bf16_t;
typedef __bf16 bf16x8 __attribute__((ext_vector_type(8)));
typedef float f32x4 __attribute__((ext_vector_type(4)));

#define GLOAD_LDS16(g, l)                                               \
  __builtin_amdgcn_global_load_lds(                                     \
      (const __attribute__((address_space(1))) void*)(g),               \
      (__attribute__((address_space(3))) void*)(l), 16, 0, 0)

#define WAITVM(N) asm volatile("s_waitcnt vmcnt(" #N ")" ::: "memory")
#define SBAR() __builtin_amdgcn_s_barrier()

// Bijective XCD-chunked swizzle (requires nwg % 8 == 0).
__device__ __forceinline__ void xcd_remap(int& bx, int& by) {
  const int gx = gridDim.x;
  const int nwg = gx * gridDim.y;
  const int id = blockIdx.y * gx + blockIdx.x;
  const int nid = (id & 7) * (nwg >> 3) + (id >> 3);
  bx = nid % gx;
  by = nid / gx;
}

// ---------------------------------------------------------------------------
// prep_all: one launch for build_x + ld_out zero + (c==0) all weight prep.
// Block map: [0,2048) grid-strided build_x; then 64 W0-transpose, 256 W1,
// 256 W2, 384 W3p, 6 b3p = +966.
__global__ __launch_bounds__(256) void prep_all(
    const float* __restrict__ x1, const float* __restrict__ mask1,
    const float* __restrict__ ctx, const float* __restrict__ W0,
    const float* __restrict__ W1, const float* __restrict__ W2,
    const float* __restrict__ W3, const float* __restrict__ b3,
    bf16_t* __restrict__ X, float* __restrict__ ld_out,
    bf16_t* __restrict__ Wt0, bf16_t* __restrict__ Wt1,
    bf16_t* __restrict__ Wt2, bf16_t* __restrict__ Wt3,
    float* __restrict__ b3p, int boff, int Bc) {
  __shared__ float tile[64][65];
  const int tid = threadIdx.x;
  int id = blockIdx.x;
  if (id < 2048) {  // build_x: grid-stride over rows (G11)
    const int c = tid;
    for (int bl = id; bl < Bc; bl += 2048) {
      const size_t b = (size_t)(boff + bl);
      float v;
      if (c < 64)       v = x1[b * 64 + c];
      else if (c < 128) v = mask1[b * 64 + (c - 64)];
      else              v = ctx[b * 128 + (c - 128)];
      X[(size_t)bl * 256 + c] = (bf16_t)v;
      if (c == 0) ld_out[b] = 0.0f;
    }
    return;
  }
  id -= 2048;
  const int r4 = tid >> 6;
  const int cc = tid & 63;
  const float* W = nullptr;
  bf16_t* Wt = nullptr;
  int K = 0, N = 0, kt = 0, nt = 0;
  bool w3 = false;
  if (id < 64)       { W = W0; Wt = Wt0; K = 256;  N = 1024; kt = (id & 3) * 64;  nt = (id >> 2) * 64; }
  else if (id < 320) { int j = id - 64;  W = W1; Wt = Wt1; K = 1024; N = 1024; kt = (j & 15) * 64; nt = (j >> 4) * 64; }
  else if (id < 576) { int j = id - 320; W = W2; Wt = Wt2; K = 1024; N = 1024; kt = (j & 15) * 64; nt = (j >> 4) * 64; }
  else if (id < 960) { int j = id - 576; K = 1024; kt = (j & 15) * 64; nt = (j >> 4) * 64; w3 = true; }
  else {
    int t = (id - 960) * 256 + tid;
    if (t < 1536) { int d = t / 24, p = t % 24; b3p[t] = (p < 23) ? b3[d * 23 + p] : 0.0f; }
    return;
  }
  if (!w3) {
#pragma unroll
    for (int i = 0; i < 16; i++) {
      int r = i * 4 + r4;
      int gn = nt + cc;
      tile[r][cc] = (gn < N) ? W[(size_t)(kt + r) * N + gn] : 0.0f;
    }
    __syncthreads();
#pragma unroll
    for (int i = 0; i < 16; i++) {
      int r = i * 4 + r4;
      Wt[(size_t)(nt + r) * K + kt + cc] = (bf16_t)tile[cc][r];
    }
  } else {
    const int np = nt + cc, d = np / 24, p = np % 24;
#pragma unroll
    for (int i = 0; i < 16; i++) {
      int r = i * 4 + r4;
      tile[r][cc] = (p < 23) ? W3[(size_t)(kt + r) * 1472 + d * 23 + p] : 0.0f;
    }
    __syncthreads();
#pragma unroll
    for (int i = 0; i < 16; i++) {
      int r = i * 4 + r4;
      Wt3[(size_t)(nt + r) * 1024 + kt + cc] = (bf16_t)tile[cc][r];
    }
  }
}

// ---------------------------------------------------------------------------
// GEMM: 256x256 tile, BK=64, 8 waves 2Mx4N (wave out 128x64, acc[8][4]).
// 8-phase pipelined schedule — byte-identical to R17 (verified, fast).
__global__ __launch_bounds__(512, 2) void gemm_bt(
    const bf16_t* __restrict__ A, const bf16_t* __restrict__ Bt,
    const float* __restrict__ bias, bf16_t* __restrict__ Cout, int N, int K) {
  __shared__ __align__(16) bf16_t sm[65536];  // 128 KB
  const int tid = threadIdx.x;
  const int lane = tid & 63;
  const int w = tid >> 6;
  int bx, by;
  xcd_remap(bx, by);
  const int m0 = by * 256;
  const int n0 = bx * 256;
  const int wmi = w >> 2;
  const int wnj = w & 3;
  const int lrow = lane & 15;
  const int quad = lane >> 4;

  const int byteoff = tid * 16;
  const int srow = byteoff >> 6;
  const int sqs = ((byteoff >> 4) & 3) ^ ((srow >> 1) & 3);
  const bf16_t* gA0 = A + (size_t)(m0 + srow) * K + sqs * 8;
  const bf16_t* gA1 = A + (size_t)(m0 + 128 + srow) * K + sqs * 8;
  const bf16_t* gB0 = Bt + (size_t)(n0 + srow) * K + sqs * 8;
  const bf16_t* gB1 = Bt + (size_t)(n0 + 128 + srow) * K + sqs * 8;
  const int dstT = tid * 8;

#define ST_A(PTR, D, RH)                                                 \
  do {                                                                   \
    GLOAD_LDS16(PTR, sm + (D) * 16384 + (RH) * 8192 + dstT);             \
    GLOAD_LDS16(PTR + 32, sm + (D) * 16384 + (RH) * 8192 + 4096 + dstT); \
    PTR += 64;                                                           \
  } while (0)
#define ST_B(PTR, D, CH)                                                 \
  do {                                                                   \
    GLOAD_LDS16(PTR, sm + 32768 + (D) * 16384 + (CH) * 8192 + dstT);     \
    GLOAD_LDS16(PTR + 32,                                                \
                sm + 32768 + (D) * 16384 + (CH) * 8192 + 4096 + dstT);   \
    PTR += 64;                                                           \
  } while (0)

  int aoff[8];
#pragma unroll
  for (int mi = 0; mi < 8; mi++) {
    const int r = mi * 16 + lrow;
    aoff[mi] = wmi * 8192 + r * 32 + (quad ^ ((r >> 1) & 3)) * 8;
  }
  int boff[4];
#pragma unroll
  for (int nj = 0; nj < 4; nj++) {
    const int c = (wnj & 1) * 64 + nj * 16 + lrow;
    boff[nj] = 32768 + (wnj >> 1) * 8192 + c * 32 + (quad ^ ((c >> 1) & 3)) * 8;
  }

#define RD_AF(DST, D, MIB)                                               \
  _Pragma("unroll") for (int q = 0; q < 4; q++)                          \
    _Pragma("unroll") for (int kk = 0; kk < 2; kk++)                     \
      DST[q][kk] =                                                       \
          *(const bf16x8*)(sm + (D) * 16384 + kk * 4096 + aoff[(MIB) + q]);
#define RD_BF(DST, D, NJB)                                               \
  _Pragma("unroll") for (int q = 0; q < 2; q++)                          \
    _Pragma("unroll") for (int kk = 0; kk < 2; kk++)                     \
      DST[q][kk] =                                                       \
          *(const bf16x8*)(sm + (D) * 16384 + kk * 4096 + boff[(NJB) + q]);
#define MM(AF, BF, MIB, NJB)                                             \
  __builtin_amdgcn_s_setprio(1);                                         \
  _Pragma("unroll") for (int q = 0; q < 4; q++)                          \
    _Pragma("unroll") for (int p = 0; p < 2; p++)                        \
      _Pragma("unroll") for (int kk = 0; kk < 2; kk++)                   \
        acc[(MIB) + q][(NJB) + p] = __builtin_amdgcn_mfma_f32_16x16x32_bf16( \
            AF[q][kk], BF[p][kk], acc[(MIB) + q][(NJB) + p], 0, 0, 0);   \
  __builtin_amdgcn_s_setprio(0);

  f32x4 acc[8][4];
#pragma unroll
  for (int i = 0; i < 8; i++)
#pragma unroll
    for (int j = 0; j < 4; j++) acc[i][j] = (f32x4){0.f, 0.f, 0.f, 0.f};

  ST_A(gA0, 0, 0);
  ST_A(gA1, 0, 1);
  ST_B(gB0, 0, 0);
  ST_B(gB1, 0, 1);
  ST_A(gA0, 1, 0);
  ST_A(gA1, 1, 1);

  const int nI = K >> 7;
  for (int i = 0; i < nI; i++) {
    const bool nl = (i + 1 < nI);
    bf16x8 afA[4][2], afB[4][2], bfrA[2][2], bfrB[2][2];
    WAITVM(4);
    SBAR();
    ST_B(gB0, 1, 0);
    RD_AF(afA, 0, 0);
    RD_BF(bfrA, 0, 0);
    MM(afA, bfrA, 0, 0);
    SBAR();
    ST_B(gB1, 1, 1);
    RD_AF(afB, 0, 4);
    MM(afB, bfrA, 4, 0);
    SBAR();
    if (nl) ST_A(gA0, 0, 0);
    RD_BF(bfrB, 0, 2);
    MM(afA, bfrB, 0, 2);
    SBAR();
    if (nl) ST_A(gA1, 0, 1);
    MM(afB, bfrB, 4, 2);
    if (nl) { WAITVM(4); } else { WAITVM(0); }
    SBAR();
    if (nl) ST_B(gB0, 0, 0);
    RD_AF(afA, 1, 0);
    RD_BF(bfrA, 1, 0);
    MM(afA, bfrA, 0, 0);
    SBAR();
    if (nl) ST_B(gB1, 0, 1);
    RD_AF(afB, 1, 4);
    MM(afB, bfrA, 4, 0);
    SBAR();
    if (nl) ST_A(gA0, 1, 0);
    RD_BF(bfrB, 1, 2);
    MM(afA, bfrB, 0, 2);
    SBAR();
    if (nl) ST_A(gA1, 1, 1);
    MM(afB, bfrB, 4, 2);
  }
#undef ST_A
#undef ST_B
#undef RD_AF
#undef RD_BF
#undef MM

  float bv[4];
#pragma unroll
  for (int j = 0; j < 4; j++) bv[j] = bias[n0 + wnj * 64 + j * 16 + lrow];
#pragma unroll
  for (int i = 0; i < 8; i++) {
    int rbase = m0 + wmi * 128 + i * 16 + quad * 4;
#pragma unroll
    for (int j = 0; j < 4; j++) {
      int col = n0 + wnj * 64 + j * 16 + lrow;
#pragma unroll
      for (int r = 0; r < 4; r++) {
        float v = fmaxf(acc[i][j][r] + bv[j], 0.0f);
        Cout[(size_t)(rbase + r) * N + col] = (bf16_t)v;
      }
    }
  }
}

// ---------------------------------------------------------------------------
// Fused last GEMM + RQ spline (R15 form, proven). Tile 128x192 (= 8 dims x
// 24 padded params), 8 waves 2x4, wave 64x48. bf16 Pt union (stride 200,
// 51200B -> 3 blocks/CU). XCD-chunked remap. R20: fast transcendentals.
__global__ __launch_bounds__(512, 4) void gemm_rq_fused(
    const bf16_t* __restrict__ A, const bf16_t* __restrict__ Bt,
    const float* __restrict__ b3p, const float* __restrict__ x2,
    float* __restrict__ z_out, float* __restrict__ ld_out,
    int boff, int K) {
  union alignas(16) SM {
    struct { bf16_t As[2][128 * 32]; bf16_t Bs[2][192 * 32]; } s;  // 40960 B
    bf16_t Pt[128 * 200];                                          // 51200 B
  };
  __shared__ SM sm;
  const int tid = threadIdx.x;
  const int w = tid >> 6;          // 0..7
  const int lane = tid & 63;
  int bx, by;
  xcd_remap(bx, by);
  const int m0 = by * 128;
  const int n0 = bx * 192;
  const int wm = (w & 1) * 64;
  const int wn = (w >> 1) * 48;    // 0..144
  const int lrow = lane & 15;
  const int quad = lane >> 4;

  bf16_t* const smB = &sm.s.As[0][0];
  // Layout (elems): As[0]@0, As[1]@4096, Bs[0]@8192, Bs[1]@14336.

  const bf16_t* gA;
  {
    const int byteoff = (w << 10) + lane * 16;
    const int row = byteoff >> 6;
    const int qs = ((byteoff >> 4) & 3) ^ ((row >> 1) & 3);
    gA = A + (size_t)(m0 + row) * K + qs * 8;
  }
  const bf16_t* gB0;
  const bf16_t* gB1;
  {
    int byteoff = (w << 10) + lane * 16;
    int row = byteoff >> 6;
    int qs = ((byteoff >> 4) & 3) ^ ((row >> 1) & 3);
    gB0 = Bt + (size_t)(n0 + row) * K + qs * 8;
    const int c1 = (w & 3) + 8;              // only used when w < 4
    byteoff = (c1 << 10) + lane * 16;
    row = byteoff >> 6;
    qs = ((byteoff >> 4) & 3) ^ ((row >> 1) & 3);
    gB1 = Bt + (size_t)(n0 + row) * K + qs * 8;
  }
  bf16_t* const dA0 = smB + w * 512;                    // h=1 at +4096
  bf16_t* const dB0 = smB + 8192 + w * 512;             // h=1 at +6144
  bf16_t* const dB1 = smB + 8192 + ((w & 3) + 8) * 512;

  int offA[4], offB3[3];
#pragma unroll
  for (int i = 0; i < 4; i++) {
    const int rowA = wm + i * 16 + lrow;
    offA[i] = rowA * 32 + (quad ^ ((rowA >> 1) & 3)) * 8;
  }
#pragma unroll
  for (int j = 0; j < 3; j++) {
    const int rowB = wn + j * 16 + lrow;
    offB3[j] = rowB * 32 + (quad ^ ((rowB >> 1) & 3)) * 8;
  }

  f32x4 acc[4][3];
#pragma unroll
  for (int i = 0; i < 4; i++)
#pragma unroll
    for (int j = 0; j < 3; j++) acc[i][j] = (f32x4){0.f, 0.f, 0.f, 0.f};

  const int nPair = K >> 6;
  for (int kp = 0; kp < nPair; kp++) {
    GLOAD_LDS16(gA, dA0);
    GLOAD_LDS16(gA + 32, dA0 + 4096);
    GLOAD_LDS16(gB0, dB0);
    GLOAD_LDS16(gB0 + 32, dB0 + 6144);
    if (w < 4) {  // wave-uniform
      GLOAD_LDS16(gB1, dB1);
      GLOAD_LDS16(gB1 + 32, dB1 + 6144);
      gB1 += 64;
    }
    gA += 64;
    gB0 += 64;
    __syncthreads();
#pragma unroll
    for (int h = 0; h < 2; h++) {
      bf16x8 af[4], bfr[3];
#pragma unroll
      for (int i = 0; i < 4; i++)
        af[i] = *(const bf16x8*)(smB + h * 4096 + offA[i]);
#pragma unroll
      for (int j = 0; j < 3; j++)
        bfr[j] = *(const bf16x8*)(smB + 8192 + h * 6144 + offB3[j]);
#pragma unroll
      for (int i = 0; i < 4; i++)
#pragma unroll
        for (int j = 0; j < 3; j++)
          acc[i][j] = __builtin_amdgcn_mfma_f32_16x16x32_bf16(
              af[i], bfr[j], acc[i][j], 0, 0, 0);
    }
    __syncthreads();
  }

  // --- P-tile (bf16, +bias) into LDS. C/D layout: col=lane&15, row=quad*4+r.
  float bv[3];
#pragma unroll
  for (int j = 0; j < 3; j++) bv[j] = b3p[n0 + wn + j * 16 + lrow];
#pragma unroll
  for (int i = 0; i < 4; i++) {
    const int rbase = wm + i * 16 + quad * 4;
#pragma unroll
    for (int j = 0; j < 3; j++) {
      const int col = wn + j * 16 + lrow;
#pragma unroll
      for (int r = 0; r < 4; r++)
        sm.Pt[(rbase + r) * 200 + col] = (bf16_t)(acc[i][j][r] + bv[j]);
    }
  }
  __syncthreads();

  // --- spline: thread t handles rows (t>>3) and (t>>3)+64, dim t&7.
  const float SHIFT = 0.54132485f;     // log(e-1)
  const float SHIFT_DX = 5.1944682f;   // log(exp(6.0-0.8)-1)
  const float left = -3.0f;
  const float delta_x = 0.8f + log1pf(expf(SHIFT_DX));
  const float right = left + delta_x;
  const float scale = delta_x;
  const int dloc = tid & 7;
  const int dg = bx * 8 + dloc;

#pragma unroll
  for (int rr = 0; rr < 2; rr++) {
    const int row = (tid >> 3) + rr * 64;
    const bf16_t* pr = sm.Pt + row * 200 + dloc * 24;
    const size_t bg = (size_t)(boff + m0 + row);
    const float x = x2[bg * 64 + dg];

    bf16x8 v0 = *(const bf16x8*)(pr);
    bf16x8 v1 = *(const bf16x8*)(pr + 8);
    bf16x8 v2 = *(const bf16x8*)(pr + 16);
    float pv[24];
#pragma unroll
    for (int j = 0; j < 8; j++) pv[j] = (float)v0[j];
#pragma unroll
    for (int j = 0; j < 8; j++) pv[8 + j] = (float)v1[j];
#pragma unroll
    for (int j = 0; j < 8; j++) pv[16 + j] = (float)v2[j];

    float mw = pv[0];
#pragma unroll
    for (int j = 1; j < 8; j++) mw = fmaxf(mw, pv[j]);
    float ew[8], swv = 0.f;
#pragma unroll
    for (int j = 0; j < 8; j++) { ew[j] = __expf(pv[j] - mw); swv += ew[j]; }
    float invw = 1.0f / swv;
    float cw[9];
    cw[0] = left;
    float cum = 0.f;
#pragma unroll
    for (int j = 0; j < 8; j++) {
      cum += 0.1f + 0.2f * ew[j] * invw;
      cw[j + 1] = left + scale * cum;
    }
    float mh = pv[8];
#pragma unroll
    for (int j = 9; j < 16; j++) mh = fmaxf(mh, pv[j]);
    float eh[8], shv = 0.f;
#pragma unroll
    for (int j = 0; j < 8; j++) { eh[j] = __expf(pv[8 + j] - mh); shv += eh[j]; }
    float invh = 1.0f / shv;
    float chh[9];
    chh[0] = left;
    float cumh = 0.f;
#pragma unroll
    for (int j = 0; j < 8; j++) {
      cumh += 0.1f + 0.2f * eh[j] * invh;
      chh[j + 1] = left + scale * cumh;
    }
    float dv[9];
    dv[0] = 1.0f;
    dv[8] = 1.0f;
#pragma unroll
    for (int j = 0; j < 7; j++) {
      float v = pv[16 + j] + SHIFT;
      dv[j + 1] = 0.001f + ((v > 20.f) ? v : log1pf(__expf(v)));
    }
    int cnt = 0;
#pragma unroll
    for (int j = 0; j < 8; j++) cnt += (cw[j] <= x) ? 1 : 0;
    cnt += ((cw[8] + 1e-6f) <= x) ? 1 : 0;
    int idx = cnt - 1;
    idx = idx < 0 ? 0 : (idx > 7 ? 7 : idx);
    float x_k = cw[0], x_k1 = cw[1], y_k = chh[0], y_k1 = chh[1];
    float d0v = dv[0], d1v = dv[1];
#pragma unroll
    for (int j = 1; j < 8; j++) {
      bool s = (idx == j);
      x_k = s ? cw[j] : x_k;
      x_k1 = s ? cw[j + 1] : x_k1;
      y_k = s ? chh[j] : y_k;
      y_k1 = s ? chh[j + 1] : y_k1;
      d0v = s ? dv[j] : d0v;
      d1v = s ? dv[j + 1] : d1v;
    }
    float x_kd = x_k1 - x_k;
    float y_kd = y_k1 - y_k;
    float s_k = y_kd / x_kd;
    float xi = (x - x_k) / x_kd;
    float xi1m = xi * (1.f - xi);
    float alpha_k = y_kd * (s_k * xi * xi + d0v * xi1m);
    float beta_k = s_k + (d1v + d0v - 2.f * s_k) * xi1m;
    float z_sp = y_k + alpha_k / fmaxf(beta_k, 1e-8f);
    float oxi = 1.f - xi;
    float num = s_k * s_k * (d1v * xi * xi + 2.f * s_k * xi1m + d0v * oxi * oxi);
    float ld_sp = __logf(fmaxf(num, 1e-8f)) - 2.f * __logf(fmaxf(beta_k, 1e-8f));

    bool inside = (left <= x) && (x < right);
    z_out[bg * 64 + dg] = inside ? z_sp : x;
    float ldv = inside ? ld_sp : 0.f;
    ldv += __shfl_xor(ldv, 1);
    ldv += __shfl_xor(ldv, 2);
    ldv += __shfl_xor(ldv, 4);
    if (dloc == 0) atomicAdd(&ld_out[bg], ldv);
  }
}

// ---------------------------------------------------------------------------
extern "C" void kernel_launch(void* const* d_in, const int* in_sizes, int n_in,
                              void* d_out, int out_size, void* d_ws,
                              size_t ws_size, hipStream_t stream) {
  const float* x1 = (const float*)d_in[0];
  const float* x2 = (const float*)d_in[1];
  const float* ctx = (const float*)d_in[2];
  const float* mask1 = (const float*)d_in[3];
  const float* W0 = (const float*)d_in[4];
  const float* b0 = (const float*)d_in[5];
  const float* W1 = (const float*)d_in[6];
  const float* b1 = (const float*)d_in[7];
  const float* W2 = (const float*)d_in[8];
  const float* b2 = (const float*)d_in[9];
  const float* W3 = (const float*)d_in[10];
  const float* b3 = (const float*)d_in[11];
  float* out = (float*)d_out;

  const int B = 65536;
  char* ws = (char*)d_ws;

  bf16_t* Wt0 = (bf16_t*)ws;                           // 1024x256  (512 KB)
  bf16_t* Wt1 = (bf16_t*)(ws + 524288);                // 1024x1024 (2 MB)
  bf16_t* Wt2 = (bf16_t*)(ws + 524288 + 2097152);      // 1024x1024 (2 MB)
  bf16_t* Wt3 = (bf16_t*)(ws + 524288 + 2 * 2097152);  // 1536x1024 (3 MB)
  float* b3p = (float*)(ws + 524288 + 2 * 2097152 + 3145728);  // 6 KB
  const size_t wend = 524288 + 2 * 2097152 + 3145728 + 8192;

  int C = 4;
  if (wend + (size_t)B * 4096 <= ws_size) C = 1;
  else if (wend + (size_t)(B / 2) * 4096 <= ws_size) C = 2;
  const int Bc = B / C;
  bf16_t* HA = (bf16_t*)(ws + wend);
  char* R = ws + wend + (size_t)Bc * 2048;
  bf16_t* X = (bf16_t*)R;
  bf16_t* HB = (bf16_t*)R;
  float* ld_out = out + (size_t)B * 64;

  for (int c = 0; c < C; c++) {
    const int boff = c * Bc;
    prep_all<<<2048 + (c == 0 ? 966 : 0), 256, 0, stream>>>(
        x1, mask1, ctx, W0, W1, W2, W3, b3, X, ld_out,
        Wt0, Wt1, Wt2, Wt3, b3p, boff, Bc);
    gemm_bt<<<dim3(4, Bc / 256), 512, 0, stream>>>(X, Wt0, b0, HA, 1024, 256);
    gemm_bt<<<dim3(4, Bc / 256), 512, 0, stream>>>(HA, Wt1, b1, HB, 1024, 1024);
    gemm_bt<<<dim3(4, Bc / 256), 512, 0, stream>>>(HB, Wt2, b2, HA, 1024, 1024);
    gemm_rq_fused<<<dim3(8, Bc / 128), 512, 0, stream>>>(
        HA, Wt3, b3p, x2, out, ld_out, boff, 1024);
  }
}

// Round 13
// 721.140 us; speedup vs baseline: 1.0766x; 1.0217x over previous
//
#include <hip/hip_runtime.h>

// RationalQuadratic: 4-layer MLP conditioner (bf16 MFMA GEMMs) + RQ spline.
// R21: R20 (best, 737us) + vectorized build_x in prep_all. Evidence: the
// build_x section wrote X via scalar 2B bf16 stores / scalar 4B loads
// (G13 violation, ~130MB of traffic). Now thread=(row-off, col-group):
// two float4 loads + one 16B bf16x8 store per 8 cols (8-col groups never
// straddle the x1/mask1/ctx boundaries). Everything else frozen:
// gemm_bt = R17 8-phase 256^2 (verified win), fused = R15 2-barrier form
// + fast transcendentals (R20), prep merge (R18), XCD remap (R15).
// Noise calibration (rule #19): fused source identical across R15-R20
// measured 152-194us -> sub-15us single-round deltas are noise.

typedef __bf16 bf16_t;
typedef __bf16 bf16x8 __attribute__((ext_vector_type(8)));
typedef float f32x4 __attribute__((ext_vector_type(4)));

#define GLOAD_LDS16(g, l)                                               \
  __builtin_amdgcn_global_load_lds(                                     \
      (const __attribute__((address_space(1))) void*)(g),               \
      (__attribute__((address_space(3))) void*)(l), 16, 0, 0)

#define WAITVM(N) asm volatile("s_waitcnt vmcnt(" #N ")" ::: "memory")
#define SBAR() __builtin_amdgcn_s_barrier()

// Bijective XCD-chunked swizzle (requires nwg % 8 == 0).
__device__ __forceinline__ void xcd_remap(int& bx, int& by) {
  const int gx = gridDim.x;
  const int nwg = gx * gridDim.y;
  const int id = blockIdx.y * gx + blockIdx.x;
  const int nid = (id & 7) * (nwg >> 3) + (id >> 3);
  bx = nid % gx;
  by = nid / gx;
}

// ---------------------------------------------------------------------------
// prep_all: one launch for build_x + ld_out zero + (c==0) all weight prep.
// Block map: [0,2048) grid-strided vectorized build_x (8 rows x 32
// col-groups per pass); then 64 W0-transpose, 256 W1, 256 W2, 384 W3p,
// 6 b3p = +966.
__global__ __launch_bounds__(256) void prep_all(
    const float* __restrict__ x1, const float* __restrict__ mask1,
    const float* __restrict__ ctx, const float* __restrict__ W0,
    const float* __restrict__ W1, const float* __restrict__ W2,
    const float* __restrict__ W3, const float* __restrict__ b3,
    bf16_t* __restrict__ X, float* __restrict__ ld_out,
    bf16_t* __restrict__ Wt0, bf16_t* __restrict__ Wt1,
    bf16_t* __restrict__ Wt2, bf16_t* __restrict__ Wt3,
    float* __restrict__ b3p, int boff, int Bc) {
  __shared__ float tile[64][65];
  const int tid = threadIdx.x;
  int id = blockIdx.x;
  if (id < 2048) {  // build_x: vectorized (G13), grid-stride over rows
    const int cg = tid & 31;   // col-group: 8 cols each
    const int ro = tid >> 5;   // 8 rows per 256-thread pass
    for (int bl = id * 8 + ro; bl < Bc; bl += 16384) {
      const size_t b = (size_t)(boff + bl);
      const float* src;
      int off;
      if (cg < 8)       { src = x1 + b * 64;    off = cg * 8; }
      else if (cg < 16) { src = mask1 + b * 64; off = (cg - 8) * 8; }
      else              { src = ctx + b * 128;  off = (cg - 16) * 8; }
      const float4 a = *(const float4*)(src + off);
      const float4 c2 = *(const float4*)(src + off + 4);
      bf16x8 v;
      v[0] = (bf16_t)a.x;  v[1] = (bf16_t)a.y;
      v[2] = (bf16_t)a.z;  v[3] = (bf16_t)a.w;
      v[4] = (bf16_t)c2.x; v[5] = (bf16_t)c2.y;
      v[6] = (bf16_t)c2.z; v[7] = (bf16_t)c2.w;
      *(bf16x8*)(X + (size_t)bl * 256 + cg * 8) = v;
      if (cg == 0) ld_out[b] = 0.0f;
    }
    return;
  }
  id -= 2048;
  const int r4 = tid >> 6;
  const int cc = tid & 63;
  const float* W = nullptr;
  bf16_t* Wt = nullptr;
  int K = 0, N = 0, kt = 0, nt = 0;
  bool w3 = false;
  if (id < 64)       { W = W0; Wt = Wt0; K = 256;  N = 1024; kt = (id & 3) * 64;  nt = (id >> 2) * 64; }
  else if (id < 320) { int j = id - 64;  W = W1; Wt = Wt1; K = 1024; N = 1024; kt = (j & 15) * 64; nt = (j >> 4) * 64; }
  else if (id < 576) { int j = id - 320; W = W2; Wt = Wt2; K = 1024; N = 1024; kt = (j & 15) * 64; nt = (j >> 4) * 64; }
  else if (id < 960) { int j = id - 576; K = 1024; kt = (j & 15) * 64; nt = (j >> 4) * 64; w3 = true; }
  else {
    int t = (id - 960) * 256 + tid;
    if (t < 1536) { int d = t / 24, p = t % 24; b3p[t] = (p < 23) ? b3[d * 23 + p] : 0.0f; }
    return;
  }
  if (!w3) {
#pragma unroll
    for (int i = 0; i < 16; i++) {
      int r = i * 4 + r4;
      int gn = nt + cc;
      tile[r][cc] = (gn < N) ? W[(size_t)(kt + r) * N + gn] : 0.0f;
    }
    __syncthreads();
#pragma unroll
    for (int i = 0; i < 16; i++) {
      int r = i * 4 + r4;
      Wt[(size_t)(nt + r) * K + kt + cc] = (bf16_t)tile[cc][r];
    }
  } else {
    const int np = nt + cc, d = np / 24, p = np % 24;
#pragma unroll
    for (int i = 0; i < 16; i++) {
      int r = i * 4 + r4;
      tile[r][cc] = (p < 23) ? W3[(size_t)(kt + r) * 1472 + d * 23 + p] : 0.0f;
    }
    __syncthreads();
#pragma unroll
    for (int i = 0; i < 16; i++) {
      int r = i * 4 + r4;
      Wt3[(size_t)(nt + r) * 1024 + kt + cc] = (bf16_t)tile[cc][r];
    }
  }
}

// ---------------------------------------------------------------------------
// GEMM: 256x256 tile, BK=64, 8 waves 2Mx4N (wave out 128x64, acc[8][4]).
// 8-phase pipelined schedule — byte-identical to R17 (verified, fast).
__global__ __launch_bounds__(512, 2) void gemm_bt(
    const bf16_t* __restrict__ A, const bf16_t* __restrict__ Bt,
    const float* __restrict__ bias, bf16_t* __restrict__ Cout, int N, int K) {
  __shared__ __align__(16) bf16_t sm[65536];  // 128 KB
  const int tid = threadIdx.x;
  const int lane = tid & 63;
  const int w = tid >> 6;
  int bx, by;
  xcd_remap(bx, by);
  const int m0 = by * 256;
  const int n0 = bx * 256;
  const int wmi = w >> 2;
  const int wnj = w & 3;
  const int lrow = lane & 15;
  const int quad = lane >> 4;

  const int byteoff = tid * 16;
  const int srow = byteoff >> 6;
  const int sqs = ((byteoff >> 4) & 3) ^ ((srow >> 1) & 3);
  const bf16_t* gA0 = A + (size_t)(m0 + srow) * K + sqs * 8;
  const bf16_t* gA1 = A + (size_t)(m0 + 128 + srow) * K + sqs * 8;
  const bf16_t* gB0 = Bt + (size_t)(n0 + srow) * K + sqs * 8;
  const bf16_t* gB1 = Bt + (size_t)(n0 + 128 + srow) * K + sqs * 8;
  const int dstT = tid * 8;

#define ST_A(PTR, D, RH)                                                 \
  do {                                                                   \
    GLOAD_LDS16(PTR, sm + (D) * 16384 + (RH) * 8192 + dstT);             \
    GLOAD_LDS16(PTR + 32, sm + (D) * 16384 + (RH) * 8192 + 4096 + dstT); \
    PTR += 64;                                                           \
  } while (0)
#define ST_B(PTR, D, CH)                                                 \
  do {                                                                   \
    GLOAD_LDS16(PTR, sm + 32768 + (D) * 16384 + (CH) * 8192 + dstT);     \
    GLOAD_LDS16(PTR + 32,                                                \
                sm + 32768 + (D) * 16384 + (CH) * 8192 + 4096 + dstT);   \
    PTR += 64;                                                           \
  } while (0)

  int aoff[8];
#pragma unroll
  for (int mi = 0; mi < 8; mi++) {
    const int r = mi * 16 + lrow;
    aoff[mi] = wmi * 8192 + r * 32 + (quad ^ ((r >> 1) & 3)) * 8;
  }
  int boff[4];
#pragma unroll
  for (int nj = 0; nj < 4; nj++) {
    const int c = (wnj & 1) * 64 + nj * 16 + lrow;
    boff[nj] = 32768 + (wnj >> 1) * 8192 + c * 32 + (quad ^ ((c >> 1) & 3)) * 8;
  }

#define RD_AF(DST, D, MIB)                                               \
  _Pragma("unroll") for (int q = 0; q < 4; q++)                          \
    _Pragma("unroll") for (int kk = 0; kk < 2; kk++)                     \
      DST[q][kk] =                                                       \
          *(const bf16x8*)(sm + (D) * 16384 + kk * 4096 + aoff[(MIB) + q]);
#define RD_BF(DST, D, NJB)                                               \
  _Pragma("unroll") for (int q = 0; q < 2; q++)                          \
    _Pragma("unroll") for (int kk = 0; kk < 2; kk++)                     \
      DST[q][kk] =                                                       \
          *(const bf16x8*)(sm + (D) * 16384 + kk * 4096 + boff[(NJB) + q]);
#define MM(AF, BF, MIB, NJB)                                             \
  __builtin_amdgcn_s_setprio(1);                                         \
  _Pragma("unroll") for (int q = 0; q < 4; q++)                          \
    _Pragma("unroll") for (int p = 0; p < 2; p++)                        \
      _Pragma("unroll") for (int kk = 0; kk < 2; kk++)                   \
        acc[(MIB) + q][(NJB) + p] = __builtin_amdgcn_mfma_f32_16x16x32_bf16( \
            AF[q][kk], BF[p][kk], acc[(MIB) + q][(NJB) + p], 0, 0, 0);   \
  __builtin_amdgcn_s_setprio(0);

  f32x4 acc[8][4];
#pragma unroll
  for (int i = 0; i < 8; i++)
#pragma unroll
    for (int j = 0; j < 4; j++) acc[i][j] = (f32x4){0.f, 0.f, 0.f, 0.f};

  ST_A(gA0, 0, 0);
  ST_A(gA1, 0, 1);
  ST_B(gB0, 0, 0);
  ST_B(gB1, 0, 1);
  ST_A(gA0, 1, 0);
  ST_A(gA1, 1, 1);

  const int nI = K >> 7;
  for (int i = 0; i < nI; i++) {
    const bool nl = (i + 1 < nI);
    bf16x8 afA[4][2], afB[4][2], bfrA[2][2], bfrB[2][2];
    WAITVM(4);
    SBAR();
    ST_B(gB0, 1, 0);
    RD_AF(afA, 0, 0);
    RD_BF(bfrA, 0, 0);
    MM(afA, bfrA, 0, 0);
    SBAR();
    ST_B(gB1, 1, 1);
    RD_AF(afB, 0, 4);
    MM(afB, bfrA, 4, 0);
    SBAR();
    if (nl) ST_A(gA0, 0, 0);
    RD_BF(bfrB, 0, 2);
    MM(afA, bfrB, 0, 2);
    SBAR();
    if (nl) ST_A(gA1, 0, 1);
    MM(afB, bfrB, 4, 2);
    if (nl) { WAITVM(4); } else { WAITVM(0); }
    SBAR();
    if (nl) ST_B(gB0, 0, 0);
    RD_AF(afA, 1, 0);
    RD_BF(bfrA, 1, 0);
    MM(afA, bfrA, 0, 0);
    SBAR();
    if (nl) ST_B(gB1, 0, 1);
    RD_AF(afB, 1, 4);
    MM(afB, bfrA, 4, 0);
    SBAR();
    if (nl) ST_A(gA0, 1, 0);
    RD_BF(bfrB, 1, 2);
    MM(afA, bfrB, 0, 2);
    SBAR();
    if (nl) ST_A(gA1, 1, 1);
    MM(afB, bfrB, 4, 2);
  }
#undef ST_A
#undef ST_B
#undef RD_AF
#undef RD_BF
#undef MM

  float bv[4];
#pragma unroll
  for (int j = 0; j < 4; j++) bv[j] = bias[n0 + wnj * 64 + j * 16 + lrow];
#pragma unroll
  for (int i = 0; i < 8; i++) {
    int rbase = m0 + wmi * 128 + i * 16 + quad * 4;
#pragma unroll
    for (int j = 0; j < 4; j++) {
      int col = n0 + wnj * 64 + j * 16 + lrow;
#pragma unroll
      for (int r = 0; r < 4; r++) {
        float v = fmaxf(acc[i][j][r] + bv[j], 0.0f);
        Cout[(size_t)(rbase + r) * N + col] = (bf16_t)v;
      }
    }
  }
}

// ---------------------------------------------------------------------------
// Fused last GEMM + RQ spline (R15 form, proven). Tile 128x192 (= 8 dims x
// 24 padded params), 8 waves 2x4, wave 64x48. bf16 Pt union (stride 200,
// 51200B -> 3 blocks/CU). XCD-chunked remap. Fast transcendentals (R20).
__global__ __launch_bounds__(512, 4) void gemm_rq_fused(
    const bf16_t* __restrict__ A, const bf16_t* __restrict__ Bt,
    const float* __restrict__ b3p, const float* __restrict__ x2,
    float* __restrict__ z_out, float* __restrict__ ld_out,
    int boff, int K) {
  union alignas(16) SM {
    struct { bf16_t As[2][128 * 32]; bf16_t Bs[2][192 * 32]; } s;  // 40960 B
    bf16_t Pt[128 * 200];                                          // 51200 B
  };
  __shared__ SM sm;
  const int tid = threadIdx.x;
  const int w = tid >> 6;          // 0..7
  const int lane = tid & 63;
  int bx, by;
  xcd_remap(bx, by);
  const int m0 = by * 128;
  const int n0 = bx * 192;
  const int wm = (w & 1) * 64;
  const int wn = (w >> 1) * 48;    // 0..144
  const int lrow = lane & 15;
  const int quad = lane >> 4;

  bf16_t* const smB = &sm.s.As[0][0];
  // Layout (elems): As[0]@0, As[1]@4096, Bs[0]@8192, Bs[1]@14336.

  const bf16_t* gA;
  {
    const int byteoff = (w << 10) + lane * 16;
    const int row = byteoff >> 6;
    const int qs = ((byteoff >> 4) & 3) ^ ((row >> 1) & 3);
    gA = A + (size_t)(m0 + row) * K + qs * 8;
  }
  const bf16_t* gB0;
  const bf16_t* gB1;
  {
    int byteoff = (w << 10) + lane * 16;
    int row = byteoff >> 6;
    int qs = ((byteoff >> 4) & 3) ^ ((row >> 1) & 3);
    gB0 = Bt + (size_t)(n0 + row) * K + qs * 8;
    const int c1 = (w & 3) + 8;              // only used when w < 4
    byteoff = (c1 << 10) + lane * 16;
    row = byteoff >> 6;
    qs = ((byteoff >> 4) & 3) ^ ((row >> 1) & 3);
    gB1 = Bt + (size_t)(n0 + row) * K + qs * 8;
  }
  bf16_t* const dA0 = smB + w * 512;                    // h=1 at +4096
  bf16_t* const dB0 = smB + 8192 + w * 512;             // h=1 at +6144
  bf16_t* const dB1 = smB + 8192 + ((w & 3) + 8) * 512;

  int offA[4], offB3[3];
#pragma unroll
  for (int i = 0; i < 4; i++) {
    const int rowA = wm + i * 16 + lrow;
    offA[i] = rowA * 32 + (quad ^ ((rowA >> 1) & 3)) * 8;
  }
#pragma unroll
  for (int j = 0; j < 3; j++) {
    const int rowB = wn + j * 16 + lrow;
    offB3[j] = rowB * 32 + (quad ^ ((rowB >> 1) & 3)) * 8;
  }

  f32x4 acc[4][3];
#pragma unroll
  for (int i = 0; i < 4; i++)
#pragma unroll
    for (int j = 0; j < 3; j++) acc[i][j] = (f32x4){0.f, 0.f, 0.f, 0.f};

  const int nPair = K >> 6;
  for (int kp = 0; kp < nPair; kp++) {
    GLOAD_LDS16(gA, dA0);
    GLOAD_LDS16(gA + 32, dA0 + 4096);
    GLOAD_LDS16(gB0, dB0);
    GLOAD_LDS16(gB0 + 32, dB0 + 6144);
    if (w < 4) {  // wave-uniform
      GLOAD_LDS16(gB1, dB1);
      GLOAD_LDS16(gB1 + 32, dB1 + 6144);
      gB1 += 64;
    }
    gA += 64;
    gB0 += 64;
    __syncthreads();
#pragma unroll
    for (int h = 0; h < 2; h++) {
      bf16x8 af[4], bfr[3];
#pragma unroll
      for (int i = 0; i < 4; i++)
        af[i] = *(const bf16x8*)(smB + h * 4096 + offA[i]);
#pragma unroll
      for (int j = 0; j < 3; j++)
        bfr[j] = *(const bf16x8*)(smB + 8192 + h * 6144 + offB3[j]);
#pragma unroll
      for (int i = 0; i < 4; i++)
#pragma unroll
        for (int j = 0; j < 3; j++)
          acc[i][j] = __builtin_amdgcn_mfma_f32_16x16x32_bf16(
              af[i], bfr[j], acc[i][j], 0, 0, 0);
    }
    __syncthreads();
  }

  // --- P-tile (bf16, +bias) into LDS. C/D layout: col=lane&15, row=quad*4+r.
  float bv[3];
#pragma unroll
  for (int j = 0; j < 3; j++) bv[j] = b3p[n0 + wn + j * 16 + lrow];
#pragma unroll
  for (int i = 0; i < 4; i++) {
    const int rbase = wm + i * 16 + quad * 4;
#pragma unroll
    for (int j = 0; j < 3; j++) {
      const int col = wn + j * 16 + lrow;
#pragma unroll
      for (int r = 0; r < 4; r++)
        sm.Pt[(rbase + r) * 200 + col] = (bf16_t)(acc[i][j][r] + bv[j]);
    }
  }
  __syncthreads();

  // --- spline: thread t handles rows (t>>3) and (t>>3)+64, dim t&7.
  const float SHIFT = 0.54132485f;     // log(e-1)
  const float SHIFT_DX = 5.1944682f;   // log(exp(6.0-0.8)-1)
  const float left = -3.0f;
  const float delta_x = 0.8f + log1pf(expf(SHIFT_DX));
  const float right = left + delta_x;
  const float scale = delta_x;
  const int dloc = tid & 7;
  const int dg = bx * 8 + dloc;

#pragma unroll
  for (int rr = 0; rr < 2; rr++) {
    const int row = (tid >> 3) + rr * 64;
    const bf16_t* pr = sm.Pt + row * 200 + dloc * 24;
    const size_t bg = (size_t)(boff + m0 + row);
    const float x = x2[bg * 64 + dg];

    bf16x8 v0 = *(const bf16x8*)(pr);
    bf16x8 v1 = *(const bf16x8*)(pr + 8);
    bf16x8 v2 = *(const bf16x8*)(pr + 16);
    float pv[24];
#pragma unroll
    for (int j = 0; j < 8; j++) pv[j] = (float)v0[j];
#pragma unroll
    for (int j = 0; j < 8; j++) pv[8 + j] = (float)v1[j];
#pragma unroll
    for (int j = 0; j < 8; j++) pv[16 + j] = (float)v2[j];

    float mw = pv[0];
#pragma unroll
    for (int j = 1; j < 8; j++) mw = fmaxf(mw, pv[j]);
    float ew[8], swv = 0.f;
#pragma unroll
    for (int j = 0; j < 8; j++) { ew[j] = __expf(pv[j] - mw); swv += ew[j]; }
    float invw = 1.0f / swv;
    float cw[9];
    cw[0] = left;
    float cum = 0.f;
#pragma unroll
    for (int j = 0; j < 8; j++) {
      cum += 0.1f + 0.2f * ew[j] * invw;
      cw[j + 1] = left + scale * cum;
    }
    float mh = pv[8];
#pragma unroll
    for (int j = 9; j < 16; j++) mh = fmaxf(mh, pv[j]);
    float eh[8], shv = 0.f;
#pragma unroll
    for (int j = 0; j < 8; j++) { eh[j] = __expf(pv[8 + j] - mh); shv += eh[j]; }
    float invh = 1.0f / shv;
    float chh[9];
    chh[0] = left;
    float cumh = 0.f;
#pragma unroll
    for (int j = 0; j < 8; j++) {
      cumh += 0.1f + 0.2f * eh[j] * invh;
      chh[j + 1] = left + scale * cumh;
    }
    float dv[9];
    dv[0] = 1.0f;
    dv[8] = 1.0f;
#pragma unroll
    for (int j = 0; j < 7; j++) {
      float v = pv[16 + j] + SHIFT;
      dv[j + 1] = 0.001f + ((v > 20.f) ? v : log1pf(__expf(v)));
    }
    int cnt = 0;
#pragma unroll
    for (int j = 0; j < 8; j++) cnt += (cw[j] <= x) ? 1 : 0;
    cnt += ((cw[8] + 1e-6f) <= x) ? 1 : 0;
    int idx = cnt - 1;
    idx = idx < 0 ? 0 : (idx > 7 ? 7 : idx);
    float x_k = cw[0], x_k1 = cw[1], y_k = chh[0], y_k1 = chh[1];
    float d0v = dv[0], d1v = dv[1];
#pragma unroll
    for (int j = 1; j < 8; j++) {
      bool s = (idx == j);
      x_k = s ? cw[j] : x_k;
      x_k1 = s ? cw[j + 1] : x_k1;
      y_k = s ? chh[j] : y_k;
      y_k1 = s ? chh[j + 1] : y_k1;
      d0v = s ? dv[j] : d0v;
      d1v = s ? dv[j + 1] : d1v;
    }
    float x_kd = x_k1 - x_k;
    float y_kd = y_k1 - y_k;
    float s_k = y_kd / x_kd;
    float xi = (x - x_k) / x_kd;
    float xi1m = xi * (1.f - xi);
    float alpha_k = y_kd * (s_k * xi * xi + d0v * xi1m);
    float beta_k = s_k + (d1v + d0v - 2.f * s_k) * xi1m;
    float z_sp = y_k + alpha_k / fmaxf(beta_k, 1e-8f);
    float oxi = 1.f - xi;
    float num = s_k * s_k * (d1v * xi * xi + 2.f * s_k * xi1m + d0v * oxi * oxi);
    float ld_sp = __logf(fmaxf(num, 1e-8f)) - 2.f * __logf(fmaxf(beta_k, 1e-8f));

    bool inside = (left <= x) && (x < right);
    z_out[bg * 64 + dg] = inside ? z_sp : x;
    float ldv = inside ? ld_sp : 0.f;
    ldv += __shfl_xor(ldv, 1);
    ldv += __shfl_xor(ldv, 2);
    ldv += __shfl_xor(ldv, 4);
    if (dloc == 0) atomicAdd(&ld_out[bg], ldv);
  }
}

// ---------------------------------------------------------------------------
extern "C" void kernel_launch(void* const* d_in, const int* in_sizes, int n_in,
                              void* d_out, int out_size, void* d_ws,
                              size_t ws_size, hipStream_t stream) {
  const float* x1 = (const float*)d_in[0];
  const float* x2 = (const float*)d_in[1];
  const float* ctx = (const float*)d_in[2];
  const float* mask1 = (const float*)d_in[3];
  const float* W0 = (const float*)d_in[4];
  const float* b0 = (const float*)d_in[5];
  const float* W1 = (const float*)d_in[6];
  const float* b1 = (const float*)d_in[7];
  const float* W2 = (const float*)d_in[8];
  const float* b2 = (const float*)d_in[9];
  const float* W3 = (const float*)d_in[10];
  const float* b3 = (const float*)d_in[11];
  float* out = (float*)d_out;

  const int B = 65536;
  char* ws = (char*)d_ws;

  bf16_t* Wt0 = (bf16_t*)ws;                           // 1024x256  (512 KB)
  bf16_t* Wt1 = (bf16_t*)(ws + 524288);                // 1024x1024 (2 MB)
  bf16_t* Wt2 = (bf16_t*)(ws + 524288 + 2097152);      // 1024x1024 (2 MB)
  bf16_t* Wt3 = (bf16_t*)(ws + 524288 + 2 * 2097152);  // 1536x1024 (3 MB)
  float* b3p = (float*)(ws + 524288 + 2 * 2097152 + 3145728);  // 6 KB
  const size_t wend = 524288 + 2 * 2097152 + 3145728 + 8192;

  int C = 4;
  if (wend + (size_t)B * 4096 <= ws_size) C = 1;
  else if (wend + (size_t)(B / 2) * 4096 <= ws_size) C = 2;
  const int Bc = B / C;
  bf16_t* HA = (bf16_t*)(ws + wend);
  char* R = ws + wend + (size_t)Bc * 2048;
  bf16_t* X = (bf16_t*)R;
  bf16_t* HB = (bf16_t*)R;
  float* ld_out = out + (size_t)B * 64;

  for (int c = 0; c < C; c++) {
    const int boff = c * Bc;
    prep_all<<<2048 + (c == 0 ? 966 : 0), 256, 0, stream>>>(
        x1, mask1, ctx, W0, W1, W2, W3, b3, X, ld_out,
        Wt0, Wt1, Wt2, Wt3, b3p, boff, Bc);
    gemm_bt<<<dim3(4, Bc / 256), 512, 0, stream>>>(X, Wt0, b0, HA, 1024, 256);
    gemm_bt<<<dim3(4, Bc / 256), 512, 0, stream>>>(HA, Wt1, b1, HB, 1024, 1024);
    gemm_bt<<<dim3(4, Bc / 256), 512, 0, stream>>>(HB, Wt2, b2, HA, 1024, 1024);
    gemm_rq_fused<<<dim3(8, Bc / 128), 512, 0, stream>>>(
        HA, Wt3, b3p, x2, out, ld_out, boff, 1024);
  }
}